// Round 1
// 1038.461 us; speedup vs baseline: 1.0634x; 1.0634x over previous
//
#include <hip/hip_runtime.h>
#include <math.h>

typedef __bf16 bf16;
typedef __bf16 bf16x8 __attribute__((ext_vector_type(8)));
typedef __bf16 bf16x4 __attribute__((ext_vector_type(4)));
typedef float  f32x4  __attribute__((ext_vector_type(4)));

// Problem constants
#define D_   768
#define E_   1536
#define S_   128
#define TT_  32768     // B*G*N tokens
#define B_   8

// ---------------- workspace layout (bytes) ----------------
#define OFF_W1T   0UL                       // 3200x768 bf16  = 4,915,200
#define OFF_W2T   4915200UL                 // 768x1536 bf16  = 2,359,296
#define OFF_TAB   7274496UL                 // 4096x64 float2 = 2,097,152
#define OFF_XN    9375744UL                 // 32768x768 bf16 = 50,331,648
#define OFF_KER   OFF_XN                    //   reuse: 128x256x256 bf16 = 16,777,216
#define OFF_QQ    (OFF_XN + 16777216UL)     //   reuse: 32768x128 bf16  =  8,388,608
#define OFF_QK    (OFF_XN + 25165824UL)     //   reuse: 8,388,608
#define OFF_LQ    (OFF_XN + 33554432UL)     //   reuse: 8,388,608 (ends XN+41.9M < 50.3M)
#define OFF_U     59707392UL                // 32768x1536 bf16 = 100,663,296 (combine in-place -> P)
#define OFF_Z     160370688UL               // 32768x128 bf16 ; reuse: P2 f32 (same 8,388,608 bytes)
#define OFF_LK    168759296UL               // 8,388,608 ; reuse: T1
#define OFF_LQT   177147904UL               // 8,388,608 ; reuse: amix (4,194,304) + kvT (3,145,728)
#define OFF_LKT   185536512UL               // 8,388,608
#define OFF_MASK  193925120UL               // 8x16x16 f32 = 8,192 (FULL size)
#define OFF_INVF  193933312UL               // 64 f32 -> end 193,933,568 (~185 MiB)

// ---------------- async global->LDS staging (m97 structure) ----------------
__device__ __forceinline__ void gl_lds16(const bf16* g, bf16* l) {
  __builtin_amdgcn_global_load_lds(
      (const __attribute__((address_space(1))) unsigned int*)g,
      (__attribute__((address_space(3))) unsigned int*)l, 16, 0, 0);
}

// ---------------- generic MFMA GEMM: C[M,N] = A[M,K] * B[N,K]^T ----------------
#define BM 128
#define BN 128
#define BK 32

template <class Epi, bool DUAL, bool SWZ = false>
__global__ __launch_bounds__(256) void gemm_bt(
    const bf16* __restrict__ A, const bf16* __restrict__ B,
    int lda, int ldb, int K,
    long sAb, long sAg, long sBb, long sBg,
    const bf16* __restrict__ A2, const bf16* __restrict__ B2,
    int lda2, int ldb2, int K2,
    long sA2b, long sA2g, long sB2b, long sB2g,
    int gdiv, Epi epi)
{
  __shared__ bf16 As[BM * BK];   // 8 KB, rows of 64 B, unpadded (global_load_lds layout)
  __shared__ bf16 Bs[BN * BK];
  const int z = blockIdx.z;
  const int bb = z / gdiv, gg = z % gdiv;

  // block raster: XCD-bijective chunking (m204) + GROUP_M supertiles for L2 reuse
  int bx = blockIdx.x, by = blockIdx.y;
  if constexpr (SWZ) {
    const int nbx = gridDim.x, nby = gridDim.y, nwg = nbx * nby;
    int bid = by * nbx + bx;
    const int q = nwg >> 3, r = nwg & 7;
    const int xcd = bid & 7, lid = bid >> 3;
    bid = (xcd < r ? xcd * (q + 1) : r * (q + 1) + (xcd - r) * q) + lid;
    const int gm = 8;
    const int pig = gm * nby;
    const int grp = bid / pig;
    const int fm = grp * gm;
    const int szm = min(nbx - fm, gm);
    const int loc = bid - grp * pig;
    bx = fm + loc % szm;
    by = loc / szm;
  }

  const int tid  = threadIdx.x;
  const int lane = tid & 63, wave = tid >> 6;
  const int wm = (wave >> 1) * 64, wn = (wave & 1) * 64;
  const int lrow = lane & 15, quad = lane >> 4;
  const int srow = wave * 16 + (lane >> 2);
  const int scol = (lane & 3) * 8;
  bf16* ldsA0 = As + wave * 512;            // 16 rows * 32 elem
  bf16* ldsA1 = As + (wave + 4) * 512;
  bf16* ldsB0 = Bs + wave * 512;
  bf16* ldsB1 = Bs + (wave + 4) * 512;

  f32x4 acc[4][4] = {};

  auto kloop = [&](const bf16* __restrict__ Ab, const bf16* __restrict__ Bb,
                   int lda_, int ldb_, int K_) {
    for (int k0 = 0; k0 < K_; k0 += BK) {
      __syncthreads();   // previous tile's ds_reads done before overwrite
      gl_lds16(Ab + (long)srow * lda_ + k0 + scol,        ldsA0);
      gl_lds16(Ab + (long)(srow + 64) * lda_ + k0 + scol, ldsA1);
      gl_lds16(Bb + (long)srow * ldb_ + k0 + scol,        ldsB0);
      gl_lds16(Bb + (long)(srow + 64) * ldb_ + k0 + scol, ldsB1);
      __syncthreads();   // compiler drains vmcnt(0) before s_barrier => LDS writes visible
      bf16x8 af[4], bfr[4];
#pragma unroll
      for (int i = 0; i < 4; i++) af[i]  = *(const bf16x8*)&As[(wm + i * 16 + lrow) * BK + quad * 8];
#pragma unroll
      for (int i = 0; i < 4; i++) bfr[i] = *(const bf16x8*)&Bs[(wn + i * 16 + lrow) * BK + quad * 8];
#pragma unroll
      for (int mi = 0; mi < 4; mi++)
#pragma unroll
        for (int ni = 0; ni < 4; ni++)
          acc[mi][ni] = __builtin_amdgcn_mfma_f32_16x16x32_bf16(af[mi], bfr[ni], acc[mi][ni], 0, 0, 0);
    }
  };

  kloop(A + (long)bb * sAb + (long)gg * sAg + (long)bx * BM * lda,
        B + (long)bb * sBb + (long)gg * sBg + (long)by * BN * ldb, lda, ldb, K);
  if constexpr (DUAL)
    kloop(A2 + (long)bb * sA2b + (long)gg * sA2g + (long)bx * BM * lda2,
          B2 + (long)bb * sB2b + (long)gg * sB2g + (long)by * BN * ldb2, lda2, ldb2, K2);

  // C/D layout: col = lane&15, row = quad*4 + j  [verified m89/m91]
  const int rowbase = bx * BM + wm + quad * 4;
  const int colbase = by * BN + wn + lrow;
#pragma unroll
  for (int mi = 0; mi < 4; mi++)
#pragma unroll
    for (int ni = 0; ni < 4; ni++)
      epi(rowbase + mi * 16, colbase + ni * 16, bb, gg, acc[mi][ni]);
}

// ---------------- epilogues (a[j] belongs to row row0+j, fixed col) ----------------
struct EpiGemm1 {   // silu(x@W1 + b1) -> u, v (direct into vT layout), z
  const float* b1; bf16* u; bf16* vT; bf16* z;
  __device__ void operator()(int row0, int col, int, int, f32x4 a) const {
    float s[4];
    const float bias = b1[col];
#pragma unroll
    for (int j = 0; j < 4; j++) {
      float x = a[j] + bias;
      // fast silu: v_exp + v_rcp path; output is bf16, approx error invisible
      float e = __expf(-x);
      s[j] = __fdividef(x, 1.f + e);
    }
    if (col < E_) {
#pragma unroll
      for (int j = 0; j < 4; j++) u[(long)(row0 + j) * E_ + col] = (bf16)s[j];
    } else if (col < 2 * E_) {
      const int e = col - E_, b = row0 >> 12, t = row0 & 4095;
      bf16x4 o;
#pragma unroll
      for (int j = 0; j < 4; j++) o[j] = (bf16)s[j];
      *(bf16x4*)&vT[((long)(b * E_ + e)) * 4096 + t] = o;
    } else {
      const int sc = col - 2 * E_;
#pragma unroll
      for (int j = 0; j < 4; j++) z[(long)(row0 + j) * S_ + sc] = (bf16)s[j];
    }
  }
};
struct EpiF32 {
  float* C; long sCb, sCg; int ldc;
  __device__ void operator()(int row0, int col, int bb, int gg, f32x4 a) const {
#pragma unroll
    for (int j = 0; j < 4; j++)
      C[(long)bb * sCb + (long)gg * sCg + (long)(row0 + j) * ldc + col] = a[j];
  }
};
struct EpiBf16 {
  bf16* C; long sCb, sCg; int ldc;
  __device__ void operator()(int row0, int col, int bb, int gg, f32x4 a) const {
#pragma unroll
    for (int j = 0; j < 4; j++)
      C[(long)bb * sCb + (long)gg * sCg + (long)(row0 + j) * ldc + col] = (bf16)a[j];
  }
};
struct EpiKer {   // relu(qk/n + w_rel[511+col-row])^2
  bf16* C; const float* wrel;
  __device__ void operator()(int row0, int col, int bb, int, f32x4 a) const {
#pragma unroll
    for (int j = 0; j < 4; j++) {
      float v = a[j] * (1.f / 256.f) + wrel[511 + col - (row0 + j)];
      v = fmaxf(v, 0.f);
      C[(long)bb * 65536 + (long)(row0 + j) * 256 + col] = (bf16)(v * v);
    }
  }
};
struct EpiCombine {   // P = u * (quadratic + linear), in-place over u
  bf16* u;
  __device__ void operator()(int row0, int col, int bb, int gg, f32x4 a) const {
#pragma unroll
    for (int j = 0; j < 4; j++) {
      long idx = ((long)((bb * 16 + gg) * 256 + row0 + j)) * E_ + col;
      u[idx] = (bf16)((float)u[idx] * a[j]);
    }
  }
};
struct EpiFinal {   // out = P@W2 + b2 + shortcut
  float* out; const float* b2; const float* x0;
  __device__ void operator()(int row0, int col, int, int, f32x4 a) const {
#pragma unroll
    for (int j = 0; j < 4; j++) {
      long idx = (long)(row0 + j) * D_ + col;
      out[idx] = a[j] + b2[col] + x0[idx];
    }
  }
};

// ---------------- LayerNorm -> bf16 ----------------
__global__ __launch_bounds__(256) void ln_kernel(
    const float* __restrict__ x, const float* __restrict__ w,
    const float* __restrict__ b, bf16* __restrict__ xn)
{
  const long t = blockIdx.x;
  const float* row = x + t * D_;
  const int tid = threadIdx.x;
  float v0 = row[tid], v1 = row[tid + 256], v2 = row[tid + 512];
  float s = v0 + v1 + v2;
  float sq = v0 * v0 + v1 * v1 + v2 * v2;
#pragma unroll
  for (int off = 32; off; off >>= 1) {
    s  += __shfl_down(s, off, 64);
    sq += __shfl_down(sq, off, 64);
  }
  __shared__ float red[2][4];
  const int wave = tid >> 6, lane = tid & 63;
  if (lane == 0) { red[0][wave] = s; red[1][wave] = sq; }
  __syncthreads();
  s  = red[0][0] + red[0][1] + red[0][2] + red[0][3];
  sq = red[1][0] + red[1][1] + red[1][2] + red[1][3];
  const float mean = s * (1.f / 768.f);
  const float var  = sq * (1.f / 768.f) - mean * mean;
  const float rs   = rsqrtf(var + 1e-5f);
  xn[t * D_ + tid]       = (bf16)((v0 - mean) * rs * w[tid] + b[tid]);
  xn[t * D_ + tid + 256] = (bf16)((v1 - mean) * rs * w[tid + 256] + b[tid + 256]);
  xn[t * D_ + tid + 512] = (bf16)((v2 - mean) * rs * w[tid + 512] + b[tid + 512]);
}

// ---------------- tiled transpose + cast to bf16 ----------------
template <class TI>
__global__ __launch_bounds__(256) void transpose_cast(
    const TI* __restrict__ in, bf16* __restrict__ out,
    int R, int C, long sInB, long sOutB)
{
  __shared__ float tile[64][65];
  const TI* ib = in  + (long)blockIdx.z * sInB;
  bf16*     ob = out + (long)blockIdx.z * sOutB;
  const int c0 = blockIdx.x * 64, r0 = blockIdx.y * 64;
  const int lc = threadIdx.x & 63, lr0 = threadIdx.x >> 6;
#pragma unroll
  for (int i = 0; i < 16; i++) {
    int r = lr0 + i * 4;
    tile[r][lc] = (float)ib[(long)(r0 + r) * C + c0 + lc];
  }
  __syncthreads();
#pragma unroll
  for (int i = 0; i < 16; i++) {
    int r = lr0 + i * 4;
    ob[(long)(c0 + r) * R + r0 + lc] = (bf16)tile[lc][r];
  }
}

// ---------------- RoPE sin/cos table ----------------
__global__ __launch_bounds__(256) void rope_table_kernel(
    const float* __restrict__ invf, float2* __restrict__ tab)
{
  int idx = blockIdx.x * 256 + threadIdx.x;   // 4096*64 entries
  int p = idx >> 6, i = idx & 63;
  float arg = (float)p * invf[i];
  double a = (double)arg;
  tab[idx] = make_float2((float)sin(a), (float)cos(a));
}

// ---------------- z -> gamma/beta -> rope -> 4 gate rows ----------------
__global__ __launch_bounds__(128) void rope_kernel(
    const bf16* __restrict__ zbuf, const float* __restrict__ gamma,
    const float* __restrict__ beta, const float2* __restrict__ tab,
    bf16* __restrict__ qq, bf16* __restrict__ qk,
    bf16* __restrict__ lq, bf16* __restrict__ lk)
{
  const long t = blockIdx.x;
  const int s = threadIdx.x;
  const int p = (int)(t & 4095);
  const int i = s & 63;
  const float2 sc = tab[p * 64 + i];
  const bf16* zr = zbuf + t * S_;
  const float zlo = (float)zr[i], zhi = (float)zr[i + 64];
  bf16* outs[4] = {qq, qk, lq, lk};
#pragma unroll
  for (int r = 0; r < 4; r++) {
    float zl = zlo * gamma[r * 128 + i]      + beta[r * 128 + i];
    float zh = zhi * gamma[r * 128 + i + 64] + beta[r * 128 + i + 64];
    float val = (s < 64) ? (zl * sc.y - zh * sc.x) : (zh * sc.y + zl * sc.x);
    outs[r][t * S_ + s] = (bf16)val;
  }
}

// ---------------- segment mask ----------------
__global__ __launch_bounds__(64) void mask_kernel(const int* __restrict__ seg, float* __restrict__ mask) {
  __shared__ int mn[16], mx[16];
  const int b = blockIdx.x, tid = threadIdx.x;
  if (tid < 16) {
    const int* p = seg + (long)b * 4096 + tid * 256;
    int lo = p[0], hi = p[0];
    for (int i = 1; i < 256; i++) { int v = p[i]; lo = min(lo, v); hi = max(hi, v); }
    mn[tid] = lo; mx[tid] = hi;
  }
  __syncthreads();
  if (tid < 16) {
    const int g = tid;
    float row[16]; float s = 0.f;
    for (int h = 0; h < 16; h++) {
      float o = (mn[g] <= mx[h] && mx[g] >= mn[h]) ? 1.f : 0.f;
      row[h] = o; s += o;
    }
    const float inv = 1.f / s;
    for (int h = 0; h < 16; h++) mask[((long)b * 16 + g) * 16 + h] = row[h] * inv;
  }
}

// ---------------- mask-mix of P2 (folds 1/n) ----------------
__global__ __launch_bounds__(256) void mix_kernel(
    const float* __restrict__ P2, const float* __restrict__ mask, bf16* __restrict__ amix)
{
  const int z = blockIdx.x;          // b*16 + g
  const int b = z >> 4;
  float m[16];
#pragma unroll
  for (int h = 0; h < 16; h++) m[h] = mask[(long)z * 16 + h] * (1.f / 256.f);
  const float* Pb = P2 + (long)b * 16 * 16384;
  bf16* Ab = amix + (long)z * 16384;
#pragma unroll 4
  for (int j = 0; j < 16; j++) {
    int c = j * 256 + threadIdx.x;   // float4 chunk id (4096 per matrix)
    float ax = 0, ay = 0, az = 0, aw = 0;
#pragma unroll
    for (int h = 0; h < 16; h++) {
      float4 p = ((const float4*)(Pb + (long)h * 16384))[c];
      ax += m[h] * p.x; ay += m[h] * p.y; az += m[h] * p.z; aw += m[h] * p.w;
    }
    bf16x4 o; o[0] = (bf16)ax; o[1] = (bf16)ay; o[2] = (bf16)az; o[3] = (bf16)aw;
    *(bf16x4*)&Ab[(long)c * 4] = o;
  }
}

// ---------------- launch ----------------
extern "C" void kernel_launch(void* const* d_in, const int* in_sizes, int n_in,
                              void* d_out, int out_size, void* d_ws, size_t ws_size,
                              hipStream_t stream)
{
  const float* x0    = (const float*)d_in[0];
  const int*   seg   = (const int*)d_in[1];
  const float* lnw   = (const float*)d_in[2];
  const float* lnb   = (const float*)d_in[3];
  const float* W1    = (const float*)d_in[4];
  const float* b1    = (const float*)d_in[5];
  const float* gamma = (const float*)d_in[6];
  const float* beta  = (const float*)d_in[7];
  const float* W2    = (const float*)d_in[8];
  const float* b2    = (const float*)d_in[9];
  const float* wrel  = (const float*)d_in[10];
  float* out = (float*)d_out;
  char* ws = (char*)d_ws;

  bf16*   w1t   = (bf16*)(ws + OFF_W1T);
  bf16*   w2t   = (bf16*)(ws + OFF_W2T);
  float2* tab   = (float2*)(ws + OFF_TAB);
  bf16*   xn    = (bf16*)(ws + OFF_XN);
  bf16*   ker   = (bf16*)(ws + OFF_KER);
  bf16*   qq    = (bf16*)(ws + OFF_QQ);
  bf16*   qk    = (bf16*)(ws + OFF_QK);
  bf16*   lq    = (bf16*)(ws + OFF_LQ);
  bf16*   u     = (bf16*)(ws + OFF_U);
  bf16*   zb    = (bf16*)(ws + OFF_Z);
  float*  P2    = (float*)(ws + OFF_Z);       // reuse (z dead after rope)
  bf16*   lk    = (bf16*)(ws + OFF_LK);
  bf16*   T1    = (bf16*)(ws + OFF_LK);       // reuse (lk dead after lkT)
  bf16*   lqT   = (bf16*)(ws + OFF_LQT);
  bf16*   amix  = (bf16*)(ws + OFF_LQT);      // reuse (lqT dead after P2)
  bf16*   kvT   = (bf16*)(ws + OFF_LQT + 4194304UL);
  bf16*   lkT   = (bf16*)(ws + OFF_LKT);
  float*  maskb = (float*)(ws + OFF_MASK);
  float*  invfd = (float*)(ws + OFF_INVF);
  bf16*   vTd   = (bf16*)d_out;               // vT lives in d_out (exact fit), dead before final GEMM

  static float h_invf[64];
  for (int i = 0; i < 64; i++) h_invf[i] = powf(10000.0f, (float)i * (1.0f / 64.0f));
  hipMemcpyAsync(invfd, h_invf, 64 * sizeof(float), hipMemcpyHostToDevice, stream);

  // prep (independent)
  transpose_cast<float><<<dim3(50, 12, 1), 256, 0, stream>>>(W1, w1t, 768, 3200, 0, 0);
  transpose_cast<float><<<dim3(12, 24, 1), 256, 0, stream>>>(W2, w2t, 1536, 768, 0, 0);
  rope_table_kernel<<<1024, 256, 0, stream>>>(invfd, tab);
  mask_kernel<<<8, 64, 0, stream>>>(seg, maskb);

  // LN -> xn (bf16)
  ln_kernel<<<TT_, 256, 0, stream>>>(x0, lnw, lnb, xn);

  // GEMM1: silu(xn@W1 + b1) -> u, vT(d_out), z   [SWZ raster]
  gemm_bt<EpiGemm1, false, true><<<dim3(256, 25, 1), 256, 0, stream>>>(
      xn, w1t, 768, 768, 768, 0, 0, 0, 0,
      nullptr, nullptr, 0, 0, 0, 0, 0, 0, 0, 1, EpiGemm1{b1, u, vTd, zb});

  // z -> 4 rope'd gate rows
  rope_kernel<<<TT_, 128, 0, stream>>>(zb, gamma, beta, tab, qq, qk, lq, lk);

  // lq/lk -> transposed (per b: 4096x128 -> 128x4096)
  transpose_cast<bf16><<<dim3(2, 64, 8), 256, 0, stream>>>(lq, lqT, 4096, 128, 524288, 524288);
  transpose_cast<bf16><<<dim3(2, 64, 8), 256, 0, stream>>>(lk, lkT, 4096, 128, 524288, 524288);

  // P2[b,h][s][k] = sum_c lq[c][s] lk[c][k]  (into dead z region)
  gemm_bt<EpiF32, false><<<dim3(1, 1, 128), 256, 0, stream>>>(
      lqT, lkT, 4096, 4096, 256, 524288, 256, 524288, 256,
      nullptr, nullptr, 0, 0, 0, 0, 0, 0, 0, 16, EpiF32{P2, 262144, 16384, 128});

  // amix[b,g] = sum_h mask/n * P2[b,h]  (into dead lqT region)
  mix_kernel<<<128, 256, 0, stream>>>(P2, maskb, amix);

  // kvT[b][e][s] = sum_t v[t][e] lk[t][s]
  gemm_bt<EpiBf16, false><<<dim3(12, 1, 8), 256, 0, stream>>>(
      vTd, lkT, 4096, 4096, 4096, 6291456, 0, 524288, 0,
      nullptr, nullptr, 0, 0, 0, 0, 0, 0, 0, 1, EpiBf16{kvT, 196608, 0, 128});

  // T1[t][s] = sum_k lq[t][k] amix[b,g][s][k]  (into dead lk region)
  gemm_bt<EpiBf16, false><<<dim3(2, 1, 128), 256, 0, stream>>>(
      lq, amix, 128, 128, 128, 32768, 0, 16384, 0,
      nullptr, nullptr, 0, 0, 0, 0, 0, 0, 0, 1, EpiBf16{T1, 32768, 0, 128});

  // ker[b,g][n][m] = relu(qq.qk/n + bias)^2  (into dead xn region)
  gemm_bt<EpiKer, false><<<dim3(2, 2, 128), 256, 0, stream>>>(
      qq, qk, 128, 128, 128, 32768, 0, 32768, 0,
      nullptr, nullptr, 0, 0, 0, 0, 0, 0, 0, 1, EpiKer{ker, wrel});

  // combine (dual-K): P = u * (ker@v + T1@kv), in-place over u
  gemm_bt<EpiCombine, true><<<dim3(2, 12, 128), 256, 0, stream>>>(
      ker, vTd, 256, 4096, 256, 1048576, 65536, 6291456, 256,
      T1, kvT, 128, 128, 128, 524288, 32768, 196608, 0, 16, EpiCombine{u});

  // out = P@W2 + b2 + shortcut (vT in d_out is dead now)   [SWZ raster]
  gemm_bt<EpiFinal, false, true><<<dim3(256, 6, 1), 256, 0, stream>>>(
      u, w2t, 1536, 1536, 1536, 0, 0, 0, 0,
      nullptr, nullptr, 0, 0, 0, 0, 0, 0, 0, 1, EpiFinal{out, b2, x0});
}

// Round 3
// 989.166 us; speedup vs baseline: 1.1164x; 1.0498x over previous
//
#include <hip/hip_runtime.h>
#include <math.h>

typedef __bf16 bf16;
typedef __bf16 bf16x8 __attribute__((ext_vector_type(8)));
typedef __bf16 bf16x4 __attribute__((ext_vector_type(4)));
typedef float  f32x4  __attribute__((ext_vector_type(4)));

// Problem constants
#define D_   768
#define E_   1536
#define S_   128
#define TT_  32768     // B*G*N tokens
#define B_   8

// ---------------- workspace layout (bytes) ----------------
#define OFF_W1T   0UL                       // 3200x768 bf16  = 4,915,200
#define OFF_W2T   4915200UL                 // 768x1536 bf16  = 2,359,296
#define OFF_TAB   7274496UL                 // 4096x64 float2 = 2,097,152
#define OFF_XN    9375744UL                 // 32768x768 bf16 = 50,331,648
#define OFF_KER   OFF_XN                    //   reuse: 128x256x256 bf16 = 16,777,216
#define OFF_QQ    (OFF_XN + 16777216UL)     //   reuse: 32768x128 bf16  =  8,388,608
#define OFF_QK    (OFF_XN + 25165824UL)     //   reuse: 8,388,608
#define OFF_LQ    (OFF_XN + 33554432UL)     //   reuse: 8,388,608 (ends XN+41.9M < 50.3M)
#define OFF_U     59707392UL                // 32768x1536 bf16 = 100,663,296 (combine in-place -> P)
#define OFF_Z     160370688UL               // 32768x128 bf16 ; reuse: P2 f32 (same 8,388,608 bytes)
#define OFF_LK    168759296UL               // 8,388,608 ; reuse: T1
#define OFF_LQT   177147904UL               // 8,388,608 ; reuse: amix (4,194,304) + kvT (3,145,728)
#define OFF_LKT   185536512UL               // 8,388,608
#define OFF_MASK  193925120UL               // 8x16x16 f32 = 8,192 (FULL size)
#define OFF_INVF  193933312UL               // 64 f32 -> end 193,933,568 (~185 MiB)

// ---------------- async global->LDS staging ----------------
// HW: per-lane global gather, LDS dest = wave-uniform base + lane*16.
__device__ __forceinline__ void gl_lds16(const bf16* g, bf16* l) {
  __builtin_amdgcn_global_load_lds(
      (const __attribute__((address_space(1))) unsigned int*)g,
      (__attribute__((address_space(3))) unsigned int*)l, 16, 0, 0);
}

// =================================================================
// 256x256 pipelined GEMM, 4-slot LDS rotation (T2+T3+T4+T5).
// C[M,N] = A[M,K] * B[N,K]^T ; M%256==0, N%256==0, K%32==0, K>=96.
// 512 threads = 8 waves (2M x 4N), per-wave output 128x64.
// K-window = 32. LDS: 4 slots x {A0,A1,B0,B1} halves of 128x32 bf16
// (8 KB each) = 128 KiB. Window t reads slot t&3 and stages tile t+3
// into slot (t+3)&3 (free since window t-1 ended -> WAR-safe).
// vmcnt(8) at window end = tiles t+2,t+3 in flight -> tile t+1 fully
// retired before the barrier (RAW-safe, ~3-window prefetch depth).
// LDS layout (per half): line j (128 B) holds rows {2j,2j+1}; 16B slot
// s of line j holds global chunk s^(j&7), chunk c = (row&1)*4 + quad.
// Stage pre-swizzles the GLOBAL address (LDS dest linear); fragment
// reads hit all 8 slots of each line -> conflict-free ds_read_b128.
// =================================================================

#define STG(GB, LD, KT, DSTH) do {                                        \
  const int cg_ = (lane & 7) ^ ((lane >> 3) & 7);                         \
  const int rg_ = wave * 16 + ((lane >> 3) << 1) + (cg_ >> 2);            \
  gl_lds16((GB) + (long)rg_ * (LD) + (KT) * 32 + (cg_ & 3) * 8,           \
           (DSTH) + wave * 512);                                          \
} while (0)

template <class Epi, bool SWZ>
__global__ __launch_bounds__(512, 2) void gemm8p(
    const bf16* __restrict__ A, const bf16* __restrict__ B,
    int lda, int ldb, int K, Epi epi)
{
  __shared__ bf16 smem[4][4][4096];   // [slot][A0,A1,B0,B1][128*32] = 128 KiB

  int bx = blockIdx.x, by = blockIdx.y;
  if constexpr (SWZ) {
    const int nbx = gridDim.x, nby = gridDim.y, nwg = nbx * nby;
    int bid = by * nbx + bx;
    const int q = nwg >> 3, r = nwg & 7;
    const int xcd = bid & 7, lid = bid >> 3;
    bid = (xcd < r ? xcd * (q + 1) : r * (q + 1) + (xcd - r) * q) + lid;
    const int gm = 8;
    const int pig = gm * nby;
    const int grp = bid / pig;
    const int fm = grp * gm;
    const int szm = min(nbx - fm, gm);
    const int loc = bid - grp * pig;
    bx = fm + loc % szm;
    by = loc / szm;
  }

  const int tid  = threadIdx.x;
  const int lane = tid & 63, wave = tid >> 6;
  const int wr = wave >> 2, wc = wave & 3;     // wave tile: 2M x 4N
  const int lrow = lane & 15, quad = lane >> 4;
  const int rb16 = (wc & 1) * 4;               // B fragment block base (16-row units)
  // lane-constant swizzled byte offset within a 16-row fragment block
  const int lbase = (lrow >> 1) * 128 +
                    (((((lrow & 1) << 2) | quad) ^ ((lrow >> 1) & 7)) * 16);

  const bf16* gA0 = A + (long)(bx * 256)       * lda;
  const bf16* gA1 = A + (long)(bx * 256 + 128) * lda;
  const bf16* gB0 = B + (long)(by * 256)       * ldb;
  const bf16* gB1 = B + (long)(by * 256 + 128) * ldb;

  f32x4 acc[8][4] = {};
  bf16x8 afr[4], bfrag[4];

  const int NT = K >> 5;   // K-windows of 32

  // prologue: fully stage tiles 0,1,2 (12 loads/lane)
#pragma unroll
  for (int t = 0; t < 3; ++t) {
    STG(gA0, lda, t, &smem[t][0][0]);
    STG(gA1, lda, t, &smem[t][1][0]);
    STG(gB0, ldb, t, &smem[t][2][0]);
    STG(gB1, ldb, t, &smem[t][3][0]);
  }
  asm volatile("s_waitcnt vmcnt(8)" ::: "memory");   // tile 0 retired
  __builtin_amdgcn_s_barrier();

  for (int t = 0; t < NT; ++t) {
    const int st = t & 3, sp = (t + 3) & 3;
    const bf16* aBuf = &smem[st][wr][0];
    const bf16* bBuf = &smem[st][2 + (wc >> 1)][0];
    const bool stg = (t + 3 < NT);

    // ---- phase 1: A rows 0..63 + all B frags ; stage A0,B0 of t+3 ----
#pragma unroll
    for (int mi = 0; mi < 4; ++mi)
      afr[mi] = *(const bf16x8*)((const char*)aBuf + mi * 1024 + lbase);
#pragma unroll
    for (int k = 0; k < 4; ++k)
      bfrag[k] = *(const bf16x8*)((const char*)bBuf + (rb16 + k) * 1024 + lbase);
    if (stg) { STG(gA0, lda, t + 3, &smem[sp][0][0]);
               STG(gB0, ldb, t + 3, &smem[sp][2][0]); }
    __builtin_amdgcn_sched_barrier(0);
    __builtin_amdgcn_s_barrier();
    __builtin_amdgcn_s_setprio(1);
#pragma unroll
    for (int mi = 0; mi < 4; ++mi)
#pragma unroll
      for (int n4 = 0; n4 < 4; ++n4)
        acc[mi][n4] = __builtin_amdgcn_mfma_f32_16x16x32_bf16(
            afr[mi], bfrag[n4], acc[mi][n4], 0, 0, 0);
    __builtin_amdgcn_s_setprio(0);
    __builtin_amdgcn_sched_barrier(0);
    __builtin_amdgcn_s_barrier();

    // ---- phase 2: A rows 64..127 (B reused) ; stage A1,B1 of t+3 ----
#pragma unroll
    for (int mi = 0; mi < 4; ++mi)
      afr[mi] = *(const bf16x8*)((const char*)aBuf + (4 + mi) * 1024 + lbase);
    if (stg) { STG(gA1, lda, t + 3, &smem[sp][1][0]);
               STG(gB1, ldb, t + 3, &smem[sp][3][0]); }
    __builtin_amdgcn_sched_barrier(0);
    __builtin_amdgcn_s_barrier();
    __builtin_amdgcn_s_setprio(1);
#pragma unroll
    for (int mi = 0; mi < 4; ++mi)
#pragma unroll
      for (int n4 = 0; n4 < 4; ++n4)
        acc[4 + mi][n4] = __builtin_amdgcn_mfma_f32_16x16x32_bf16(
            afr[mi], bfrag[n4], acc[4 + mi][n4], 0, 0, 0);
    __builtin_amdgcn_s_setprio(0);
    __builtin_amdgcn_sched_barrier(0);

    // ---- window end: counted drain + barrier ----
    if (t + 3 < NT)      asm volatile("s_waitcnt vmcnt(8)" ::: "memory");
    else if (t + 2 < NT) asm volatile("s_waitcnt vmcnt(4)" ::: "memory");
    else if (t + 1 < NT) asm volatile("s_waitcnt vmcnt(0)" ::: "memory");
    if (t + 1 < NT) __builtin_amdgcn_s_barrier();
  }

  // C/D layout per 16x16 frag: col = lane&15, row = quad*4 + j  [m89/m91]
  const int rowbase = bx * 256 + wr * 128 + quad * 4;
  const int colbase = by * 256 + wc * 64 + lrow;
#pragma unroll
  for (int mi = 0; mi < 8; mi++)
#pragma unroll
    for (int ni = 0; ni < 4; ni++)
      epi(rowbase + mi * 16, colbase + ni * 16, 0, 0, acc[mi][ni]);
}

// ---------------- generic MFMA GEMM (m97 structure, 128x128) ----------------
#define BM 128
#define BN 128
#define BK 32

template <class Epi, bool DUAL, bool SWZ = false>
__global__ __launch_bounds__(256) void gemm_bt(
    const bf16* __restrict__ A, const bf16* __restrict__ B,
    int lda, int ldb, int K,
    long sAb, long sAg, long sBb, long sBg,
    const bf16* __restrict__ A2, const bf16* __restrict__ B2,
    int lda2, int ldb2, int K2,
    long sA2b, long sA2g, long sB2b, long sB2g,
    int gdiv, Epi epi)
{
  __shared__ bf16 As[BM * BK];
  __shared__ bf16 Bs[BN * BK];
  const int z = blockIdx.z;
  const int bb = z / gdiv, gg = z % gdiv;

  int bx = blockIdx.x, by = blockIdx.y;
  if constexpr (SWZ) {
    const int nbx = gridDim.x, nby = gridDim.y, nwg = nbx * nby;
    int bid = by * nbx + bx;
    const int q = nwg >> 3, r = nwg & 7;
    const int xcd = bid & 7, lid = bid >> 3;
    bid = (xcd < r ? xcd * (q + 1) : r * (q + 1) + (xcd - r) * q) + lid;
    const int gm = 8;
    const int pig = gm * nby;
    const int grp = bid / pig;
    const int fm = grp * gm;
    const int szm = min(nbx - fm, gm);
    const int loc = bid - grp * pig;
    bx = fm + loc % szm;
    by = loc / szm;
  }

  const int tid  = threadIdx.x;
  const int lane = tid & 63, wave = tid >> 6;
  const int wm = (wave >> 1) * 64, wn = (wave & 1) * 64;
  const int lrow = lane & 15, quad = lane >> 4;
  const int srow = wave * 16 + (lane >> 2);
  const int scol = (lane & 3) * 8;
  bf16* ldsA0 = As + wave * 512;
  bf16* ldsA1 = As + (wave + 4) * 512;
  bf16* ldsB0 = Bs + wave * 512;
  bf16* ldsB1 = Bs + (wave + 4) * 512;

  f32x4 acc[4][4] = {};

  auto kloop = [&](const bf16* __restrict__ Ab, const bf16* __restrict__ Bb,
                   int lda_, int ldb_, int K_) {
    for (int k0 = 0; k0 < K_; k0 += BK) {
      __syncthreads();
      gl_lds16(Ab + (long)srow * lda_ + k0 + scol,        ldsA0);
      gl_lds16(Ab + (long)(srow + 64) * lda_ + k0 + scol, ldsA1);
      gl_lds16(Bb + (long)srow * ldb_ + k0 + scol,        ldsB0);
      gl_lds16(Bb + (long)(srow + 64) * ldb_ + k0 + scol, ldsB1);
      __syncthreads();
      bf16x8 af[4], bfr[4];
#pragma unroll
      for (int i = 0; i < 4; i++) af[i]  = *(const bf16x8*)&As[(wm + i * 16 + lrow) * BK + quad * 8];
#pragma unroll
      for (int i = 0; i < 4; i++) bfr[i] = *(const bf16x8*)&Bs[(wn + i * 16 + lrow) * BK + quad * 8];
#pragma unroll
      for (int mi = 0; mi < 4; mi++)
#pragma unroll
        for (int ni = 0; ni < 4; ni++)
          acc[mi][ni] = __builtin_amdgcn_mfma_f32_16x16x32_bf16(af[mi], bfr[ni], acc[mi][ni], 0, 0, 0);
    }
  };

  kloop(A + (long)bb * sAb + (long)gg * sAg + (long)bx * BM * lda,
        B + (long)bb * sBb + (long)gg * sBg + (long)by * BN * ldb, lda, ldb, K);
  if constexpr (DUAL)
    kloop(A2 + (long)bb * sA2b + (long)gg * sA2g + (long)bx * BM * lda2,
          B2 + (long)bb * sB2b + (long)gg * sB2g + (long)by * BN * ldb2, lda2, ldb2, K2);

  const int rowbase = bx * BM + wm + quad * 4;
  const int colbase = by * BN + wn + lrow;
#pragma unroll
  for (int mi = 0; mi < 4; mi++)
#pragma unroll
    for (int ni = 0; ni < 4; ni++)
      epi(rowbase + mi * 16, colbase + ni * 16, bb, gg, acc[mi][ni]);
}

// ---------------- epilogues (a[j] belongs to row row0+j, fixed col) ----------------
struct EpiGemm1 {   // silu(x@W1 + b1) -> u, v (direct into vT layout)
  const float* b1; bf16* u; bf16* vT; bf16* z;
  __device__ void operator()(int row0, int col, int, int, f32x4 a) const {
    float s[4];
    const float bias = b1[col];
#pragma unroll
    for (int j = 0; j < 4; j++) {
      float x = a[j] + bias;
      float e = __expf(-x);
      s[j] = __fdividef(x, 1.f + e);
    }
    if (col < E_) {
#pragma unroll
      for (int j = 0; j < 4; j++) u[(long)(row0 + j) * E_ + col] = (bf16)s[j];
    } else if (col < 2 * E_) {
      const int e = col - E_, b = row0 >> 12, t = row0 & 4095;
      bf16x4 o;
#pragma unroll
      for (int j = 0; j < 4; j++) o[j] = (bf16)s[j];
      *(bf16x4*)&vT[((long)(b * E_ + e)) * 4096 + t] = o;
    } else {
      const int sc = col - 2 * E_;
#pragma unroll
      for (int j = 0; j < 4; j++) z[(long)(row0 + j) * S_ + sc] = (bf16)s[j];
    }
  }
};
struct EpiZ {   // silu(x@W1[:,2E:] + b1[2E+col]) -> z
  const float* b1; bf16* z;
  __device__ void operator()(int row0, int col, int, int, f32x4 a) const {
    const float bias = b1[2 * E_ + col];
#pragma unroll
    for (int j = 0; j < 4; j++) {
      float x = a[j] + bias;
      float e = __expf(-x);
      z[(long)(row0 + j) * S_ + col] = (bf16)__fdividef(x, 1.f + e);
    }
  }
};
struct EpiF32 {
  float* C; long sCb, sCg; int ldc;
  __device__ void operator()(int row0, int col, int bb, int gg, f32x4 a) const {
#pragma unroll
    for (int j = 0; j < 4; j++)
      C[(long)bb * sCb + (long)gg * sCg + (long)(row0 + j) * ldc + col] = a[j];
  }
};
struct EpiBf16 {
  bf16* C; long sCb, sCg; int ldc;
  __device__ void operator()(int row0, int col, int bb, int gg, f32x4 a) const {
#pragma unroll
    for (int j = 0; j < 4; j++)
      C[(long)bb * sCb + (long)gg * sCg + (long)(row0 + j) * ldc + col] = (bf16)a[j];
  }
};
struct EpiKer {   // relu(qk/n + w_rel[511+col-row])^2
  bf16* C; const float* wrel;
  __device__ void operator()(int row0, int col, int bb, int, f32x4 a) const {
#pragma unroll
    for (int j = 0; j < 4; j++) {
      float v = a[j] * (1.f / 256.f) + wrel[511 + col - (row0 + j)];
      v = fmaxf(v, 0.f);
      C[(long)bb * 65536 + (long)(row0 + j) * 256 + col] = (bf16)(v * v);
    }
  }
};
struct EpiCombine {   // P = u * (quadratic + linear), in-place over u
  bf16* u;
  __device__ void operator()(int row0, int col, int bb, int gg, f32x4 a) const {
#pragma unroll
    for (int j = 0; j < 4; j++) {
      long idx = ((long)((bb * 16 + gg) * 256 + row0 + j)) * E_ + col;
      u[idx] = (bf16)((float)u[idx] * a[j]);
    }
  }
};
struct EpiFinal {   // out = P@W2 + b2 + shortcut
  float* out; const float* b2; const float* x0;
  __device__ void operator()(int row0, int col, int, int, f32x4 a) const {
#pragma unroll
    for (int j = 0; j < 4; j++) {
      long idx = (long)(row0 + j) * D_ + col;
      out[idx] = a[j] + b2[col] + x0[idx];
    }
  }
};

// ---------------- LayerNorm -> bf16 ----------------
__global__ __launch_bounds__(256) void ln_kernel(
    const float* __restrict__ x, const float* __restrict__ w,
    const float* __restrict__ b, bf16* __restrict__ xn)
{
  const long t = blockIdx.x;
  const float* row = x + t * D_;
  const int tid = threadIdx.x;
  float v0 = row[tid], v1 = row[tid + 256], v2 = row[tid + 512];
  float s = v0 + v1 + v2;
  float sq = v0 * v0 + v1 * v1 + v2 * v2;
#pragma unroll
  for (int off = 32; off; off >>= 1) {
    s  += __shfl_down(s, off, 64);
    sq += __shfl_down(sq, off, 64);
  }
  __shared__ float red[2][4];
  const int wave = tid >> 6, lane = tid & 63;
  if (lane == 0) { red[0][wave] = s; red[1][wave] = sq; }
  __syncthreads();
  s  = red[0][0] + red[0][1] + red[0][2] + red[0][3];
  sq = red[1][0] + red[1][1] + red[1][2] + red[1][3];
  const float mean = s * (1.f / 768.f);
  const float var  = sq * (1.f / 768.f) - mean * mean;
  const float rs   = rsqrtf(var + 1e-5f);
  xn[t * D_ + tid]       = (bf16)((v0 - mean) * rs * w[tid] + b[tid]);
  xn[t * D_ + tid + 256] = (bf16)((v1 - mean) * rs * w[tid + 256] + b[tid + 256]);
  xn[t * D_ + tid + 512] = (bf16)((v2 - mean) * rs * w[tid + 512] + b[tid + 512]);
}

// ---------------- tiled transpose + cast to bf16 ----------------
template <class TI>
__global__ __launch_bounds__(256) void transpose_cast(
    const TI* __restrict__ in, bf16* __restrict__ out,
    int R, int C, long sInB, long sOutB)
{
  __shared__ float tile[64][65];
  const TI* ib = in  + (long)blockIdx.z * sInB;
  bf16*     ob = out + (long)blockIdx.z * sOutB;
  const int c0 = blockIdx.x * 64, r0 = blockIdx.y * 64;
  const int lc = threadIdx.x & 63, lr0 = threadIdx.x >> 6;
#pragma unroll
  for (int i = 0; i < 16; i++) {
    int r = lr0 + i * 4;
    tile[r][lc] = (float)ib[(long)(r0 + r) * C + c0 + lc];
  }
  __syncthreads();
#pragma unroll
  for (int i = 0; i < 16; i++) {
    int r = lr0 + i * 4;
    ob[(long)(c0 + r) * R + r0 + lc] = (bf16)tile[lc][r];
  }
}

// ---------------- RoPE sin/cos table ----------------
__global__ __launch_bounds__(256) void rope_table_kernel(
    const float* __restrict__ invf, float2* __restrict__ tab)
{
  int idx = blockIdx.x * 256 + threadIdx.x;   // 4096*64 entries
  int p = idx >> 6, i = idx & 63;
  float arg = (float)p * invf[i];
  double a = (double)arg;
  tab[idx] = make_float2((float)sin(a), (float)cos(a));
}

// ---------------- z -> gamma/beta -> rope -> 4 gate rows ----------------
__global__ __launch_bounds__(128) void rope_kernel(
    const bf16* __restrict__ zbuf, const float* __restrict__ gamma,
    const float* __restrict__ beta, const float2* __restrict__ tab,
    bf16* __restrict__ qq, bf16* __restrict__ qk,
    bf16* __restrict__ lq, bf16* __restrict__ lk)
{
  const long t = blockIdx.x;
  const int s = threadIdx.x;
  const int p = (int)(t & 4095);
  const int i = s & 63;
  const float2 sc = tab[p * 64 + i];
  const bf16* zr = zbuf + t * S_;
  const float zlo = (float)zr[i], zhi = (float)zr[i + 64];
  bf16* outs[4] = {qq, qk, lq, lk};
#pragma unroll
  for (int r = 0; r < 4; r++) {
    float zl = zlo * gamma[r * 128 + i]      + beta[r * 128 + i];
    float zh = zhi * gamma[r * 128 + i + 64] + beta[r * 128 + i + 64];
    float val = (s < 64) ? (zl * sc.y - zh * sc.x) : (zh * sc.y + zl * sc.x);
    outs[r][t * S_ + s] = (bf16)val;
  }
}

// ---------------- segment mask ----------------
__global__ __launch_bounds__(64) void mask_kernel(const int* __restrict__ seg, float* __restrict__ mask) {
  __shared__ int mn[16], mx[16];
  const int b = blockIdx.x, tid = threadIdx.x;
  if (tid < 16) {
    const int* p = seg + (long)b * 4096 + tid * 256;
    int lo = p[0], hi = p[0];
    for (int i = 1; i < 256; i++) { int v = p[i]; lo = min(lo, v); hi = max(hi, v); }
    mn[tid] = lo; mx[tid] = hi;
  }
  __syncthreads();
  if (tid < 16) {
    const int g = tid;
    float row[16]; float s = 0.f;
    for (int h = 0; h < 16; h++) {
      float o = (mn[g] <= mx[h] && mx[g] >= mn[h]) ? 1.f : 0.f;
      row[h] = o; s += o;
    }
    const float inv = 1.f / s;
    for (int h = 0; h < 16; h++) mask[((long)b * 16 + g) * 16 + h] = row[h] * inv;
  }
}

// ---------------- mask-mix of P2 (folds 1/n) ----------------
__global__ __launch_bounds__(256) void mix_kernel(
    const float* __restrict__ P2, const float* __restrict__ mask, bf16* __restrict__ amix)
{
  const int z = blockIdx.x;          // b*16 + g
  const int b = z >> 4;
  float m[16];
#pragma unroll
  for (int h = 0; h < 16; h++) m[h] = mask[(long)z * 16 + h] * (1.f / 256.f);
  const float* Pb = P2 + (long)b * 16 * 16384;
  bf16* Ab = amix + (long)z * 16384;
#pragma unroll 4
  for (int j = 0; j < 16; j++) {
    int c = j * 256 + threadIdx.x;
    float ax = 0, ay = 0, az = 0, aw = 0;
#pragma unroll
    for (int h = 0; h < 16; h++) {
      float4 p = ((const float4*)(Pb + (long)h * 16384))[c];
      ax += m[h] * p.x; ay += m[h] * p.y; az += m[h] * p.z; aw += m[h] * p.w;
    }
    bf16x4 o; o[0] = (bf16)ax; o[1] = (bf16)ay; o[2] = (bf16)az; o[3] = (bf16)aw;
    *(bf16x4*)&Ab[(long)c * 4] = o;
  }
}

// ---------------- launch ----------------
extern "C" void kernel_launch(void* const* d_in, const int* in_sizes, int n_in,
                              void* d_out, int out_size, void* d_ws, size_t ws_size,
                              hipStream_t stream)
{
  const float* x0    = (const float*)d_in[0];
  const int*   seg   = (const int*)d_in[1];
  const float* lnw   = (const float*)d_in[2];
  const float* lnb   = (const float*)d_in[3];
  const float* W1    = (const float*)d_in[4];
  const float* b1    = (const float*)d_in[5];
  const float* gamma = (const float*)d_in[6];
  const float* beta  = (const float*)d_in[7];
  const float* W2    = (const float*)d_in[8];
  const float* b2    = (const float*)d_in[9];
  const float* wrel  = (const float*)d_in[10];
  float* out = (float*)d_out;
  char* ws = (char*)d_ws;

  bf16*   w1t   = (bf16*)(ws + OFF_W1T);
  bf16*   w2t   = (bf16*)(ws + OFF_W2T);
  float2* tab   = (float2*)(ws + OFF_TAB);
  bf16*   xn    = (bf16*)(ws + OFF_XN);
  bf16*   ker   = (bf16*)(ws + OFF_KER);
  bf16*   qq    = (bf16*)(ws + OFF_QQ);
  bf16*   qk    = (bf16*)(ws + OFF_QK);
  bf16*   lq    = (bf16*)(ws + OFF_LQ);
  bf16*   u     = (bf16*)(ws + OFF_U);
  bf16*   zb    = (bf16*)(ws + OFF_Z);
  float*  P2    = (float*)(ws + OFF_Z);
  bf16*   lk    = (bf16*)(ws + OFF_LK);
  bf16*   T1    = (bf16*)(ws + OFF_LK);
  bf16*   lqT   = (bf16*)(ws + OFF_LQT);
  bf16*   amix  = (bf16*)(ws + OFF_LQT);
  bf16*   kvT   = (bf16*)(ws + OFF_LQT + 4194304UL);
  bf16*   lkT   = (bf16*)(ws + OFF_LKT);
  float*  maskb = (float*)(ws + OFF_MASK);
  float*  invfd = (float*)(ws + OFF_INVF);
  bf16*   vTd   = (bf16*)d_out;

  static float h_invf[64];
  for (int i = 0; i < 64; i++) h_invf[i] = powf(10000.0f, (float)i * (1.0f / 64.0f));
  hipMemcpyAsync(invfd, h_invf, 64 * sizeof(float), hipMemcpyHostToDevice, stream);

  // prep (independent)
  transpose_cast<float><<<dim3(50, 12, 1), 256, 0, stream>>>(W1, w1t, 768, 3200, 0, 0);
  transpose_cast<float><<<dim3(12, 24, 1), 256, 0, stream>>>(W2, w2t, 1536, 768, 0, 0);
  rope_table_kernel<<<1024, 256, 0, stream>>>(invfd, tab);
  mask_kernel<<<8, 64, 0, stream>>>(seg, maskb);

  // LN -> xn (bf16)
  ln_kernel<<<TT_, 256, 0, stream>>>(x0, lnw, lnb, xn);

  // GEMM1 (u,v cols 0..3071): 4-slot pipelined 256^2
  gemm8p<EpiGemm1, true><<<dim3(128, 12), 512, 0, stream>>>(
      xn, w1t, 768, 768, 768, EpiGemm1{b1, u, vTd, zb});
  // GEMM1 z-slice (cols 3072..3199): 128^2 pass
  gemm_bt<EpiZ, false><<<dim3(256, 1, 1), 256, 0, stream>>>(
      xn, w1t + (long)3072 * 768, 768, 768, 768, 0, 0, 0, 0,
      nullptr, nullptr, 0, 0, 0, 0, 0, 0, 0, 1, EpiZ{b1, zb});

  // z -> 4 rope'd gate rows
  rope_kernel<<<TT_, 128, 0, stream>>>(zb, gamma, beta, tab, qq, qk, lq, lk);

  // lq/lk -> transposed (per b: 4096x128 -> 128x4096)
  transpose_cast<bf16><<<dim3(2, 64, 8), 256, 0, stream>>>(lq, lqT, 4096, 128, 524288, 524288);
  transpose_cast<bf16><<<dim3(2, 64, 8), 256, 0, stream>>>(lk, lkT, 4096, 128, 524288, 524288);

  // P2[b,h][s][k] = sum_c lq[c][s] lk[c][k]
  gemm_bt<EpiF32, false><<<dim3(1, 1, 128), 256, 0, stream>>>(
      lqT, lkT, 4096, 4096, 256, 524288, 256, 524288, 256,
      nullptr, nullptr, 0, 0, 0, 0, 0, 0, 0, 16, EpiF32{P2, 262144, 16384, 128});

  // amix[b,g] = sum_h mask/n * P2[b,h]
  mix_kernel<<<128, 256, 0, stream>>>(P2, maskb, amix);

  // kvT[b][e][s] = sum_t v[t][e] lk[t][s]
  gemm_bt<EpiBf16, false><<<dim3(12, 1, 8), 256, 0, stream>>>(
      vTd, lkT, 4096, 4096, 4096, 6291456, 0, 524288, 0,
      nullptr, nullptr, 0, 0, 0, 0, 0, 0, 0, 1, EpiBf16{kvT, 196608, 0, 128});

  // T1[t][s] = sum_k lq[t][k] amix[b,g][s][k]
  gemm_bt<EpiBf16, false><<<dim3(2, 1, 128), 256, 0, stream>>>(
      lq, amix, 128, 128, 128, 32768, 0, 16384, 0,
      nullptr, nullptr, 0, 0, 0, 0, 0, 0, 0, 1, EpiBf16{T1, 32768, 0, 128});

  // ker[b,g][n][m] = relu(qq.qk/n + bias)^2
  gemm_bt<EpiKer, false><<<dim3(2, 2, 128), 256, 0, stream>>>(
      qq, qk, 128, 128, 128, 32768, 0, 32768, 0,
      nullptr, nullptr, 0, 0, 0, 0, 0, 0, 0, 1, EpiKer{ker, wrel});

  // combine (dual-K): P = u * (ker@v + T1@kv), in-place over u
  gemm_bt<EpiCombine, true><<<dim3(2, 12, 128), 256, 0, stream>>>(
      ker, vTd, 256, 4096, 256, 1048576, 65536, 6291456, 256,
      T1, kvT, 128, 128, 128, 524288, 32768, 196608, 0, 16, EpiCombine{u});

  // out = P@W2 + b2 + shortcut: 4-slot pipelined 256^2
  gemm8p<EpiFinal, true><<<dim3(128, 3), 512, 0, stream>>>(
      u, w2t, 1536, 1536, 1536, EpiFinal{out, b2, x0});
}

// Round 4
// 972.484 us; speedup vs baseline: 1.1356x; 1.0172x over previous
//
#include <hip/hip_runtime.h>
#include <math.h>

typedef __bf16 bf16;
typedef __bf16 bf16x8 __attribute__((ext_vector_type(8)));
typedef __bf16 bf16x4 __attribute__((ext_vector_type(4)));
typedef float  f32x4  __attribute__((ext_vector_type(4)));

// Problem constants
#define D_   768
#define E_   1536
#define S_   128
#define TT_  32768     // B*G*N tokens
#define B_   8

// ---------------- workspace layout (bytes) ----------------
#define OFF_W1T   0UL                       // 3200x768 bf16  = 4,915,200
#define OFF_W2T   4915200UL                 // 768x1536 bf16  = 2,359,296
#define OFF_TAB   7274496UL                 // 4096x64 float2 = 2,097,152
#define OFF_XN    9375744UL                 // 32768x768 bf16 = 50,331,648
#define OFF_KER   OFF_XN                    //   reuse: 128x256x256 bf16 = 16,777,216
#define OFF_QQ    (OFF_XN + 16777216UL)     //   reuse: 32768x128 bf16  =  8,388,608
#define OFF_QK    (OFF_XN + 25165824UL)     //   reuse: 8,388,608
#define OFF_LQ    (OFF_XN + 33554432UL)     //   reuse: 8,388,608 (ends XN+41.9M < 50.3M)
#define OFF_U     59707392UL                // 32768x1536 bf16 = 100,663,296 (combine in-place -> P)
#define OFF_Z     160370688UL               // 32768x128 bf16 ; reuse: P2 f32 (same 8,388,608 bytes)
#define OFF_LK    168759296UL               // 8,388,608 ; reuse: T1
#define OFF_LQT   177147904UL               // 8,388,608 ; reuse: amix (4,194,304) + kvT (3,145,728)
#define OFF_LKT   185536512UL               // 8,388,608
#define OFF_MASK  193925120UL               // 8x16x16 f32 = 8,192 (FULL size)
#define OFF_INVF  193933312UL               // 64 f32 -> end 193,933,568 (~185 MiB)

// ---------------- async global->LDS staging ----------------
// HW: per-lane global gather, LDS dest = wave-uniform base + lane*16.
__device__ __forceinline__ void gl_lds16(const bf16* g, bf16* l) {
  __builtin_amdgcn_global_load_lds(
      (const __attribute__((address_space(1))) unsigned int*)g,
      (__attribute__((address_space(3))) unsigned int*)l, 16, 0, 0);
}

// =================================================================
// 256x256 pipelined GEMM, 4-slot LDS rotation, ONE barrier per window.
// C[M,N] = A[M,K] * B[N,K]^T ; M%256==0, N%256==0, K%32==0, K>=96.
// 512 threads = 8 waves (2M x 4N), per-wave output 128x64.
// K-window = 32. LDS: 4 slots x {A0,A1,B0,B1} halves of 128x32 bf16
// (8 KB each) = 128 KiB. Window t reads slot t&3 (read-only) and
// stages tile t+3 into slot (t+3)&3 (write-only; its last readers
// finished at the end-of-window-(t-1) barrier -> WAR-safe).
// End of window: sched_barrier(0) pins staging above the counted
// vmcnt(8) (tiles t+2,t+3 in flight -> tile t+1 fully retired on each
// issuing wave) -> RAW-safe; then ONE s_barrier. No intra-window
// barriers: waves slip, ds_read and staging fly under MFMA (compiler
// emits fine-grained lgkmcnt for the fragment deps).
// LDS layout (per half): line j (128 B) holds rows {2j,2j+1}; 16B slot
// s of line j holds global chunk s^(j&7), chunk c = (row&1)*4 + quad.
// Stage pre-swizzles the GLOBAL address (LDS dest linear); fragment
// reads hit all 8 slots of each line -> conflict-free ds_read_b128.
// =================================================================

#define STG(GB, LD, KT, DSTH) do {                                        \
  const int cg_ = (lane & 7) ^ ((lane >> 3) & 7);                         \
  const int rg_ = wave * 16 + ((lane >> 3) << 1) + (cg_ >> 2);            \
  gl_lds16((GB) + (long)rg_ * (LD) + (KT) * 32 + (cg_ & 3) * 8,           \
           (DSTH) + wave * 512);                                          \
} while (0)

template <class Epi, bool SWZ>
__global__ __launch_bounds__(512, 2) void gemm8p(
    const bf16* __restrict__ A, const bf16* __restrict__ B,
    int lda, int ldb, int K, Epi epi)
{
  __shared__ bf16 smem[4][4][4096];   // [slot][A0,A1,B0,B1][128*32] = 128 KiB

  int bx = blockIdx.x, by = blockIdx.y;
  if constexpr (SWZ) {
    const int nbx = gridDim.x, nby = gridDim.y, nwg = nbx * nby;
    int bid = by * nbx + bx;
    const int q = nwg >> 3, r = nwg & 7;
    const int xcd = bid & 7, lid = bid >> 3;
    bid = (xcd < r ? xcd * (q + 1) : r * (q + 1) + (xcd - r) * q) + lid;
    const int gm = 8;
    const int pig = gm * nby;
    const int grp = bid / pig;
    const int fm = grp * gm;
    const int szm = min(nbx - fm, gm);
    const int loc = bid - grp * pig;
    bx = fm + loc % szm;
    by = loc / szm;
  }

  const int tid  = threadIdx.x;
  const int lane = tid & 63, wave = tid >> 6;
  const int wr = wave >> 2, wc = wave & 3;     // wave tile: 2M x 4N
  const int lrow = lane & 15, quad = lane >> 4;
  const int rb16 = (wc & 1) * 4;               // B fragment block base (16-row units)
  // lane-constant swizzled byte offset within a 16-row fragment block
  const int lbase = (lrow >> 1) * 128 +
                    (((((lrow & 1) << 2) | quad) ^ ((lrow >> 1) & 7)) * 16);

  const bf16* gA0 = A + (long)(bx * 256)       * lda;
  const bf16* gA1 = A + (long)(bx * 256 + 128) * lda;
  const bf16* gB0 = B + (long)(by * 256)       * ldb;
  const bf16* gB1 = B + (long)(by * 256 + 128) * ldb;

  f32x4 acc[8][4] = {};
  bf16x8 a0[4], a1[4], bfrag[4];

  const int NT = K >> 5;   // K-windows of 32

  // prologue: fully stage tiles 0,1,2 (12 loads/lane)
#pragma unroll
  for (int t = 0; t < 3; ++t) {
    STG(gA0, lda, t, &smem[t][0][0]);
    STG(gA1, lda, t, &smem[t][1][0]);
    STG(gB0, ldb, t, &smem[t][2][0]);
    STG(gB1, ldb, t, &smem[t][3][0]);
  }
  asm volatile("s_waitcnt vmcnt(8)" ::: "memory");   // tile 0 retired
  __builtin_amdgcn_s_barrier();
  __builtin_amdgcn_sched_barrier(0);

  for (int t = 0; t < NT; ++t) {
    const int st = t & 3, sp = (t + 3) & 3;
    const bf16* aBuf = &smem[st][wr][0];
    const bf16* bBuf = &smem[st][2 + (wc >> 1)][0];

    // ---- issue all fragment reads + next staging up front ----
#pragma unroll
    for (int mi = 0; mi < 4; ++mi)
      a0[mi] = *(const bf16x8*)((const char*)aBuf + mi * 1024 + lbase);
#pragma unroll
    for (int k = 0; k < 4; ++k)
      bfrag[k] = *(const bf16x8*)((const char*)bBuf + (rb16 + k) * 1024 + lbase);
#pragma unroll
    for (int mi = 0; mi < 4; ++mi)
      a1[mi] = *(const bf16x8*)((const char*)aBuf + (4 + mi) * 1024 + lbase);
    if (t + 3 < NT) {
      STG(gA0, lda, t + 3, &smem[sp][0][0]);
      STG(gB0, ldb, t + 3, &smem[sp][2][0]);
      STG(gA1, lda, t + 3, &smem[sp][1][0]);
      STG(gB1, ldb, t + 3, &smem[sp][3][0]);
    }

    // ---- MFMA cluster 1 (a0 x bfrag): compiler waits lgkmcnt on deps ----
    __builtin_amdgcn_s_setprio(1);
#pragma unroll
    for (int mi = 0; mi < 4; ++mi)
#pragma unroll
      for (int n4 = 0; n4 < 4; ++n4)
        acc[mi][n4] = __builtin_amdgcn_mfma_f32_16x16x32_bf16(
            a0[mi], bfrag[n4], acc[mi][n4], 0, 0, 0);
    // ---- MFMA cluster 2 (a1 x bfrag) ----
#pragma unroll
    for (int mi = 0; mi < 4; ++mi)
#pragma unroll
      for (int n4 = 0; n4 < 4; ++n4)
        acc[4 + mi][n4] = __builtin_amdgcn_mfma_f32_16x16x32_bf16(
            a1[mi], bfrag[n4], acc[4 + mi][n4], 0, 0, 0);
    __builtin_amdgcn_s_setprio(0);

    // ---- window end: pin staging above the counted drain, one barrier ----
    __builtin_amdgcn_sched_barrier(0);
    if (t + 3 < NT)      asm volatile("s_waitcnt vmcnt(8)" ::: "memory");
    else if (t + 2 < NT) asm volatile("s_waitcnt vmcnt(4)" ::: "memory");
    else if (t + 1 < NT) asm volatile("s_waitcnt vmcnt(0)" ::: "memory");
    if (t + 1 < NT) {
      __builtin_amdgcn_s_barrier();
      __builtin_amdgcn_sched_barrier(0);
    }
  }

  // C/D layout per 16x16 frag: col = lane&15, row = quad*4 + j  [m89/m91]
  const int rowbase = bx * 256 + wr * 128 + quad * 4;
  const int colbase = by * 256 + wc * 64 + lrow;
#pragma unroll
  for (int mi = 0; mi < 8; mi++)
#pragma unroll
    for (int ni = 0; ni < 4; ni++)
      epi(rowbase + mi * 16, colbase + ni * 16, 0, 0, acc[mi][ni]);
}

// ---------------- generic MFMA GEMM (m97 structure, 128x128) ----------------
#define BM 128
#define BN 128
#define BK 32

template <class Epi, bool DUAL, bool SWZ = false>
__global__ __launch_bounds__(256) void gemm_bt(
    const bf16* __restrict__ A, const bf16* __restrict__ B,
    int lda, int ldb, int K,
    long sAb, long sAg, long sBb, long sBg,
    const bf16* __restrict__ A2, const bf16* __restrict__ B2,
    int lda2, int ldb2, int K2,
    long sA2b, long sA2g, long sB2b, long sB2g,
    int gdiv, Epi epi)
{
  __shared__ bf16 As[BM * BK];
  __shared__ bf16 Bs[BN * BK];
  const int z = blockIdx.z;
  const int bb = z / gdiv, gg = z % gdiv;

  int bx = blockIdx.x, by = blockIdx.y;
  if constexpr (SWZ) {
    const int nbx = gridDim.x, nby = gridDim.y, nwg = nbx * nby;
    int bid = by * nbx + bx;
    const int q = nwg >> 3, r = nwg & 7;
    const int xcd = bid & 7, lid = bid >> 3;
    bid = (xcd < r ? xcd * (q + 1) : r * (q + 1) + (xcd - r) * q) + lid;
    const int gm = 8;
    const int pig = gm * nby;
    const int grp = bid / pig;
    const int fm = grp * gm;
    const int szm = min(nbx - fm, gm);
    const int loc = bid - grp * pig;
    bx = fm + loc % szm;
    by = loc / szm;
  }

  const int tid  = threadIdx.x;
  const int lane = tid & 63, wave = tid >> 6;
  const int wm = (wave >> 1) * 64, wn = (wave & 1) * 64;
  const int lrow = lane & 15, quad = lane >> 4;
  const int srow = wave * 16 + (lane >> 2);
  const int scol = (lane & 3) * 8;
  bf16* ldsA0 = As + wave * 512;
  bf16* ldsA1 = As + (wave + 4) * 512;
  bf16* ldsB0 = Bs + wave * 512;
  bf16* ldsB1 = Bs + (wave + 4) * 512;

  f32x4 acc[4][4] = {};

  auto kloop = [&](const bf16* __restrict__ Ab, const bf16* __restrict__ Bb,
                   int lda_, int ldb_, int K_) {
    for (int k0 = 0; k0 < K_; k0 += BK) {
      __syncthreads();
      gl_lds16(Ab + (long)srow * lda_ + k0 + scol,        ldsA0);
      gl_lds16(Ab + (long)(srow + 64) * lda_ + k0 + scol, ldsA1);
      gl_lds16(Bb + (long)srow * ldb_ + k0 + scol,        ldsB0);
      gl_lds16(Bb + (long)(srow + 64) * ldb_ + k0 + scol, ldsB1);
      __syncthreads();
      bf16x8 af[4], bfr[4];
#pragma unroll
      for (int i = 0; i < 4; i++) af[i]  = *(const bf16x8*)&As[(wm + i * 16 + lrow) * BK + quad * 8];
#pragma unroll
      for (int i = 0; i < 4; i++) bfr[i] = *(const bf16x8*)&Bs[(wn + i * 16 + lrow) * BK + quad * 8];
#pragma unroll
      for (int mi = 0; mi < 4; mi++)
#pragma unroll
        for (int ni = 0; ni < 4; ni++)
          acc[mi][ni] = __builtin_amdgcn_mfma_f32_16x16x32_bf16(af[mi], bfr[ni], acc[mi][ni], 0, 0, 0);
    }
  };

  kloop(A + (long)bb * sAb + (long)gg * sAg + (long)bx * BM * lda,
        B + (long)bb * sBb + (long)gg * sBg + (long)by * BN * ldb, lda, ldb, K);
  if constexpr (DUAL)
    kloop(A2 + (long)bb * sA2b + (long)gg * sA2g + (long)bx * BM * lda2,
          B2 + (long)bb * sB2b + (long)gg * sB2g + (long)by * BN * ldb2, lda2, ldb2, K2);

  const int rowbase = bx * BM + wm + quad * 4;
  const int colbase = by * BN + wn + lrow;
#pragma unroll
  for (int mi = 0; mi < 4; mi++)
#pragma unroll
    for (int ni = 0; ni < 4; ni++)
      epi(rowbase + mi * 16, colbase + ni * 16, bb, gg, acc[mi][ni]);
}

// ---------------- epilogues (a[j] belongs to row row0+j, fixed col) ----------------
struct EpiGemm1 {   // silu(x@W1 + b1) -> u, v (direct into vT layout)
  const float* b1; bf16* u; bf16* vT; bf16* z;
  __device__ void operator()(int row0, int col, int, int, f32x4 a) const {
    float s[4];
    const float bias = b1[col];
#pragma unroll
    for (int j = 0; j < 4; j++) {
      float x = a[j] + bias;
      float e = __expf(-x);
      s[j] = __fdividef(x, 1.f + e);
    }
    if (col < E_) {
#pragma unroll
      for (int j = 0; j < 4; j++) u[(long)(row0 + j) * E_ + col] = (bf16)s[j];
    } else if (col < 2 * E_) {
      const int e = col - E_, b = row0 >> 12, t = row0 & 4095;
      bf16x4 o;
#pragma unroll
      for (int j = 0; j < 4; j++) o[j] = (bf16)s[j];
      *(bf16x4*)&vT[((long)(b * E_ + e)) * 4096 + t] = o;
    } else {
      const int sc = col - 2 * E_;
#pragma unroll
      for (int j = 0; j < 4; j++) z[(long)(row0 + j) * S_ + sc] = (bf16)s[j];
    }
  }
};
struct EpiZ {   // silu(x@W1[:,2E:] + b1[2E+col]) -> z
  const float* b1; bf16* z;
  __device__ void operator()(int row0, int col, int, int, f32x4 a) const {
    const float bias = b1[2 * E_ + col];
#pragma unroll
    for (int j = 0; j < 4; j++) {
      float x = a[j] + bias;
      float e = __expf(-x);
      z[(long)(row0 + j) * S_ + col] = (bf16)__fdividef(x, 1.f + e);
    }
  }
};
struct EpiF32 {
  float* C; long sCb, sCg; int ldc;
  __device__ void operator()(int row0, int col, int bb, int gg, f32x4 a) const {
#pragma unroll
    for (int j = 0; j < 4; j++)
      C[(long)bb * sCb + (long)gg * sCg + (long)(row0 + j) * ldc + col] = a[j];
  }
};
struct EpiBf16 {
  bf16* C; long sCb, sCg; int ldc;
  __device__ void operator()(int row0, int col, int bb, int gg, f32x4 a) const {
#pragma unroll
    for (int j = 0; j < 4; j++)
      C[(long)bb * sCb + (long)gg * sCg + (long)(row0 + j) * ldc + col] = (bf16)a[j];
  }
};
struct EpiKer {   // relu(qk/n + w_rel[511+col-row])^2
  bf16* C; const float* wrel;
  __device__ void operator()(int row0, int col, int bb, int, f32x4 a) const {
#pragma unroll
    for (int j = 0; j < 4; j++) {
      float v = a[j] * (1.f / 256.f) + wrel[511 + col - (row0 + j)];
      v = fmaxf(v, 0.f);
      C[(long)bb * 65536 + (long)(row0 + j) * 256 + col] = (bf16)(v * v);
    }
  }
};
struct EpiCombine {   // P = u * (quadratic + linear), in-place over u
  bf16* u;
  __device__ void operator()(int row0, int col, int bb, int gg, f32x4 a) const {
#pragma unroll
    for (int j = 0; j < 4; j++) {
      long idx = ((long)((bb * 16 + gg) * 256 + row0 + j)) * E_ + col;
      u[idx] = (bf16)((float)u[idx] * a[j]);
    }
  }
};
struct EpiFinal {   // out = P@W2 + b2 + shortcut
  float* out; const float* b2; const float* x0;
  __device__ void operator()(int row0, int col, int, int, f32x4 a) const {
#pragma unroll
    for (int j = 0; j < 4; j++) {
      long idx = (long)(row0 + j) * D_ + col;
      out[idx] = a[j] + b2[col] + x0[idx];
    }
  }
};

// ---------------- LayerNorm -> bf16 ----------------
__global__ __launch_bounds__(256) void ln_kernel(
    const float* __restrict__ x, const float* __restrict__ w,
    const float* __restrict__ b, bf16* __restrict__ xn)
{
  const long t = blockIdx.x;
  const float* row = x + t * D_;
  const int tid = threadIdx.x;
  float v0 = row[tid], v1 = row[tid + 256], v2 = row[tid + 512];
  float s = v0 + v1 + v2;
  float sq = v0 * v0 + v1 * v1 + v2 * v2;
#pragma unroll
  for (int off = 32; off; off >>= 1) {
    s  += __shfl_down(s, off, 64);
    sq += __shfl_down(sq, off, 64);
  }
  __shared__ float red[2][4];
  const int wave = tid >> 6, lane = tid & 63;
  if (lane == 0) { red[0][wave] = s; red[1][wave] = sq; }
  __syncthreads();
  s  = red[0][0] + red[0][1] + red[0][2] + red[0][3];
  sq = red[1][0] + red[1][1] + red[1][2] + red[1][3];
  const float mean = s * (1.f / 768.f);
  const float var  = sq * (1.f / 768.f) - mean * mean;
  const float rs   = rsqrtf(var + 1e-5f);
  xn[t * D_ + tid]       = (bf16)((v0 - mean) * rs * w[tid] + b[tid]);
  xn[t * D_ + tid + 256] = (bf16)((v1 - mean) * rs * w[tid + 256] + b[tid + 256]);
  xn[t * D_ + tid + 512] = (bf16)((v2 - mean) * rs * w[tid + 512] + b[tid + 512]);
}

// ---------------- tiled transpose + cast to bf16 ----------------
template <class TI>
__global__ __launch_bounds__(256) void transpose_cast(
    const TI* __restrict__ in, bf16* __restrict__ out,
    int R, int C, long sInB, long sOutB)
{
  __shared__ float tile[64][65];
  const TI* ib = in  + (long)blockIdx.z * sInB;
  bf16*     ob = out + (long)blockIdx.z * sOutB;
  const int c0 = blockIdx.x * 64, r0 = blockIdx.y * 64;
  const int lc = threadIdx.x & 63, lr0 = threadIdx.x >> 6;
#pragma unroll
  for (int i = 0; i < 16; i++) {
    int r = lr0 + i * 4;
    tile[r][lc] = (float)ib[(long)(r0 + r) * C + c0 + lc];
  }
  __syncthreads();
#pragma unroll
  for (int i = 0; i < 16; i++) {
    int r = lr0 + i * 4;
    ob[(long)(c0 + r) * R + r0 + lc] = (bf16)tile[lc][r];
  }
}

// ---------------- RoPE sin/cos table ----------------
__global__ __launch_bounds__(256) void rope_table_kernel(
    const float* __restrict__ invf, float2* __restrict__ tab)
{
  int idx = blockIdx.x * 256 + threadIdx.x;   // 4096*64 entries
  int p = idx >> 6, i = idx & 63;
  float arg = (float)p * invf[i];
  double a = (double)arg;
  tab[idx] = make_float2((float)sin(a), (float)cos(a));
}

// ---------------- z -> gamma/beta -> rope -> 4 gate rows ----------------
__global__ __launch_bounds__(128) void rope_kernel(
    const bf16* __restrict__ zbuf, const float* __restrict__ gamma,
    const float* __restrict__ beta, const float2* __restrict__ tab,
    bf16* __restrict__ qq, bf16* __restrict__ qk,
    bf16* __restrict__ lq, bf16* __restrict__ lk)
{
  const long t = blockIdx.x;
  const int s = threadIdx.x;
  const int p = (int)(t & 4095);
  const int i = s & 63;
  const float2 sc = tab[p * 64 + i];
  const bf16* zr = zbuf + t * S_;
  const float zlo = (float)zr[i], zhi = (float)zr[i + 64];
  bf16* outs[4] = {qq, qk, lq, lk};
#pragma unroll
  for (int r = 0; r < 4; r++) {
    float zl = zlo * gamma[r * 128 + i]      + beta[r * 128 + i];
    float zh = zhi * gamma[r * 128 + i + 64] + beta[r * 128 + i + 64];
    float val = (s < 64) ? (zl * sc.y - zh * sc.x) : (zh * sc.y + zl * sc.x);
    outs[r][t * S_ + s] = (bf16)val;
  }
}

// ---------------- segment mask ----------------
__global__ __launch_bounds__(64) void mask_kernel(const int* __restrict__ seg, float* __restrict__ mask) {
  __shared__ int mn[16], mx[16];
  const int b = blockIdx.x, tid = threadIdx.x;
  if (tid < 16) {
    const int* p = seg + (long)b * 4096 + tid * 256;
    int lo = p[0], hi = p[0];
    for (int i = 1; i < 256; i++) { int v = p[i]; lo = min(lo, v); hi = max(hi, v); }
    mn[tid] = lo; mx[tid] = hi;
  }
  __syncthreads();
  if (tid < 16) {
    const int g = tid;
    float row[16]; float s = 0.f;
    for (int h = 0; h < 16; h++) {
      float o = (mn[g] <= mx[h] && mx[g] >= mn[h]) ? 1.f : 0.f;
      row[h] = o; s += o;
    }
    const float inv = 1.f / s;
    for (int h = 0; h < 16; h++) mask[((long)b * 16 + g) * 16 + h] = row[h] * inv;
  }
}

// ---------------- mask-mix of P2 (folds 1/n) ----------------
__global__ __launch_bounds__(256) void mix_kernel(
    const float* __restrict__ P2, const float* __restrict__ mask, bf16* __restrict__ amix)
{
  const int z = blockIdx.x;          // b*16 + g
  const int b = z >> 4;
  float m[16];
#pragma unroll
  for (int h = 0; h < 16; h++) m[h] = mask[(long)z * 16 + h] * (1.f / 256.f);
  const float* Pb = P2 + (long)b * 16 * 16384;
  bf16* Ab = amix + (long)z * 16384;
#pragma unroll 4
  for (int j = 0; j < 16; j++) {
    int c = j * 256 + threadIdx.x;
    float ax = 0, ay = 0, az = 0, aw = 0;
#pragma unroll
    for (int h = 0; h < 16; h++) {
      float4 p = ((const float4*)(Pb + (long)h * 16384))[c];
      ax += m[h] * p.x; ay += m[h] * p.y; az += m[h] * p.z; aw += m[h] * p.w;
    }
    bf16x4 o; o[0] = (bf16)ax; o[1] = (bf16)ay; o[2] = (bf16)az; o[3] = (bf16)aw;
    *(bf16x4*)&Ab[(long)c * 4] = o;
  }
}

// ---------------- launch ----------------
extern "C" void kernel_launch(void* const* d_in, const int* in_sizes, int n_in,
                              void* d_out, int out_size, void* d_ws, size_t ws_size,
                              hipStream_t stream)
{
  const float* x0    = (const float*)d_in[0];
  const int*   seg   = (const int*)d_in[1];
  const float* lnw   = (const float*)d_in[2];
  const float* lnb   = (const float*)d_in[3];
  const float* W1    = (const float*)d_in[4];
  const float* b1    = (const float*)d_in[5];
  const float* gamma = (const float*)d_in[6];
  const float* beta  = (const float*)d_in[7];
  const float* W2    = (const float*)d_in[8];
  const float* b2    = (const float*)d_in[9];
  const float* wrel  = (const float*)d_in[10];
  float* out = (float*)d_out;
  char* ws = (char*)d_ws;

  bf16*   w1t   = (bf16*)(ws + OFF_W1T);
  bf16*   w2t   = (bf16*)(ws + OFF_W2T);
  float2* tab   = (float2*)(ws + OFF_TAB);
  bf16*   xn    = (bf16*)(ws + OFF_XN);
  bf16*   ker   = (bf16*)(ws + OFF_KER);
  bf16*   qq    = (bf16*)(ws + OFF_QQ);
  bf16*   qk    = (bf16*)(ws + OFF_QK);
  bf16*   lq    = (bf16*)(ws + OFF_LQ);
  bf16*   u     = (bf16*)(ws + OFF_U);
  bf16*   zb    = (bf16*)(ws + OFF_Z);
  float*  P2    = (float*)(ws + OFF_Z);
  bf16*   lk    = (bf16*)(ws + OFF_LK);
  bf16*   T1    = (bf16*)(ws + OFF_LK);
  bf16*   lqT   = (bf16*)(ws + OFF_LQT);
  bf16*   amix  = (bf16*)(ws + OFF_LQT);
  bf16*   kvT   = (bf16*)(ws + OFF_LQT + 4194304UL);
  bf16*   lkT   = (bf16*)(ws + OFF_LKT);
  float*  maskb = (float*)(ws + OFF_MASK);
  float*  invfd = (float*)(ws + OFF_INVF);
  bf16*   vTd   = (bf16*)d_out;

  static float h_invf[64];
  for (int i = 0; i < 64; i++) h_invf[i] = powf(10000.0f, (float)i * (1.0f / 64.0f));
  hipMemcpyAsync(invfd, h_invf, 64 * sizeof(float), hipMemcpyHostToDevice, stream);

  // prep (independent)
  transpose_cast<float><<<dim3(50, 12, 1), 256, 0, stream>>>(W1, w1t, 768, 3200, 0, 0);
  transpose_cast<float><<<dim3(12, 24, 1), 256, 0, stream>>>(W2, w2t, 1536, 768, 0, 0);
  rope_table_kernel<<<1024, 256, 0, stream>>>(invfd, tab);
  mask_kernel<<<8, 64, 0, stream>>>(seg, maskb);

  // LN -> xn (bf16)
  ln_kernel<<<TT_, 256, 0, stream>>>(x0, lnw, lnb, xn);

  // GEMM1 (u,v cols 0..3071): 4-slot pipelined 256^2
  gemm8p<EpiGemm1, true><<<dim3(128, 12), 512, 0, stream>>>(
      xn, w1t, 768, 768, 768, EpiGemm1{b1, u, vTd, zb});
  // GEMM1 z-slice (cols 3072..3199): 128^2 pass
  gemm_bt<EpiZ, false><<<dim3(256, 1, 1), 256, 0, stream>>>(
      xn, w1t + (long)3072 * 768, 768, 768, 768, 0, 0, 0, 0,
      nullptr, nullptr, 0, 0, 0, 0, 0, 0, 0, 1, EpiZ{b1, zb});

  // z -> 4 rope'd gate rows
  rope_kernel<<<TT_, 128, 0, stream>>>(zb, gamma, beta, tab, qq, qk, lq, lk);

  // lq/lk -> transposed (per b: 4096x128 -> 128x4096)
  transpose_cast<bf16><<<dim3(2, 64, 8), 256, 0, stream>>>(lq, lqT, 4096, 128, 524288, 524288);
  transpose_cast<bf16><<<dim3(2, 64, 8), 256, 0, stream>>>(lk, lkT, 4096, 128, 524288, 524288);

  // P2[b,h][s][k] = sum_c lq[c][s] lk[c][k]
  gemm_bt<EpiF32, false><<<dim3(1, 1, 128), 256, 0, stream>>>(
      lqT, lkT, 4096, 4096, 256, 524288, 256, 524288, 256,
      nullptr, nullptr, 0, 0, 0, 0, 0, 0, 0, 16, EpiF32{P2, 262144, 16384, 128});

  // amix[b,g] = sum_h mask/n * P2[b,h]
  mix_kernel<<<128, 256, 0, stream>>>(P2, maskb, amix);

  // kvT[b][e][s] = sum_t v[t][e] lk[t][s]
  gemm_bt<EpiBf16, false><<<dim3(12, 1, 8), 256, 0, stream>>>(
      vTd, lkT, 4096, 4096, 4096, 6291456, 0, 524288, 0,
      nullptr, nullptr, 0, 0, 0, 0, 0, 0, 0, 1, EpiBf16{kvT, 196608, 0, 128});

  // T1[t][s] = sum_k lq[t][k] amix[b,g][s][k]
  gemm_bt<EpiBf16, false><<<dim3(2, 1, 128), 256, 0, stream>>>(
      lq, amix, 128, 128, 128, 32768, 0, 16384, 0,
      nullptr, nullptr, 0, 0, 0, 0, 0, 0, 0, 1, EpiBf16{T1, 32768, 0, 128});

  // ker[b,g][n][m] = relu(qq.qk/n + bias)^2
  gemm_bt<EpiKer, false><<<dim3(2, 2, 128), 256, 0, stream>>>(
      qq, qk, 128, 128, 128, 32768, 0, 32768, 0,
      nullptr, nullptr, 0, 0, 0, 0, 0, 0, 0, 1, EpiKer{ker, wrel});

  // combine (dual-K): P = u * (ker@v + T1@kv), in-place over u
  gemm_bt<EpiCombine, true><<<dim3(2, 12, 128), 256, 0, stream>>>(
      ker, vTd, 256, 4096, 256, 1048576, 65536, 6291456, 256,
      T1, kvT, 128, 128, 128, 524288, 32768, 196608, 0, 16, EpiCombine{u});

  // out = P@W2 + b2 + shortcut: 4-slot pipelined 256^2
  gemm8p<EpiFinal, true><<<dim3(128, 3), 512, 0, stream>>>(
      u, w2t, 1536, 1536, 1536, EpiFinal{out, b2, x0});
}

// Round 5
// 942.645 us; speedup vs baseline: 1.1715x; 1.0317x over previous
//
#include <hip/hip_runtime.h>
#include <math.h>

typedef __bf16 bf16;
typedef __bf16 bf16x8 __attribute__((ext_vector_type(8)));
typedef __bf16 bf16x4 __attribute__((ext_vector_type(4)));
typedef float  f32x4  __attribute__((ext_vector_type(4)));

// Problem constants
#define D_   768
#define E_   1536
#define S_   128
#define TT_  32768     // B*G*N tokens
#define B_   8

// ---------------- workspace layout (bytes) ----------------
#define OFF_W1T   0UL                       // 3200x768 bf16  = 4,915,200
#define OFF_W2T   4915200UL                 // 768x1536 bf16  = 2,359,296
#define OFF_TAB   7274496UL                 // 4096x64 float2 = 2,097,152
#define OFF_XN    9375744UL                 // 32768x768 bf16 = 50,331,648
#define OFF_KER   OFF_XN                    //   reuse: 128x256x256 bf16 = 16,777,216
#define OFF_QQ    (OFF_XN + 16777216UL)     //   reuse: 32768x128 bf16  =  8,388,608
#define OFF_QK    (OFF_XN + 25165824UL)     //   reuse: 8,388,608
#define OFF_LQ    (OFF_XN + 33554432UL)     //   reuse: 8,388,608 (ends XN+41.9M < 50.3M)
#define OFF_U     59707392UL                // 32768x1536 bf16 = 100,663,296 (combine in-place -> P)
#define OFF_Z     160370688UL               // 32768x128 bf16 ; reuse: P2 f32 (same 8,388,608 bytes)
#define OFF_LK    168759296UL               // 8,388,608 ; reuse: T1
#define OFF_LQT   177147904UL               // 8,388,608 ; reuse: amix (4,194,304) + kvT (3,145,728)
#define OFF_LKT   185536512UL               // 8,388,608
#define OFF_MASK  193925120UL               // 8x16x16 f32 = 8,192 (FULL size)
#define OFF_INVF  193933312UL               // 64 f32 -> end 193,933,568 (~185 MiB)

// ---------------- async global->LDS staging ----------------
// HW: per-lane global gather, LDS dest = wave-uniform base + lane*16.
__device__ __forceinline__ void gl_lds16(const bf16* g, bf16* l) {
  __builtin_amdgcn_global_load_lds(
      (const __attribute__((address_space(1))) unsigned int*)g,
      (__attribute__((address_space(3))) unsigned int*)l, 16, 0, 0);
}

// =================================================================
// 128x128 pipelined GEMM, 3-slot LDS rotation, 3 blocks/CU.
// C[M,N] = A[M,K] * B[N,K]^T ; M%128==0, N%128==0, K%32==0, K>=64.
// 256 threads = 4 waves (2M x 2N), per-wave output 64x64 (acc=64 AGPR).
// K-window = 32. LDS: 3 slots x {A,B} halves of 128x32 bf16 (8 KB each)
// = 48 KiB -> 3 blocks/CU (144 KB LDS, 12 waves, ~155 regs < 512/3).
// Window t reads slot t%3 (read-only) and stages tile t+2 into slot
// (t+2)%3, whose last readers finished at the end-of-(t-1) barrier
// (WAR-safe). End of window: sched_barrier(0) pins staging above the
// counted vmcnt(4) (leaves tile t+2's 4 loads in flight; drains tile
// t+1's -> RAW-safe per wave; cross-wave via barrier-after-drain).
// Cross-block overlap (3/CU) hides prologue fill + epilogue stores.
// LDS layout (per half): line j (128 B) holds rows {2j,2j+1}; 16B slot
// s of line j holds logical chunk s^(j&7), chunk c = (row&1)*4 + quad.
// Stage pre-swizzles the GLOBAL gather address (LDS dest stays linear);
// fragment reads hit all 8 banksets -> conflict-free ds_read_b128.
// =================================================================

// stage rows [wave*32, wave*32+32) of a 128-row half (2 loads/wave)
#define STG2(GB, LD, KT, DSTH) do {                                       \
  const int cg_ = (lane & 7) ^ ((lane >> 3) & 7);                         \
  const int rg_ = wave * 32 + ((lane >> 3) << 1) + (cg_ >> 2);            \
  gl_lds16((GB) + (long)rg_ * (LD) + (KT) * 32 + (cg_ & 3) * 8,           \
           (DSTH) + wave * 1024);                                         \
  gl_lds16((GB) + (long)(rg_ + 16) * (LD) + (KT) * 32 + (cg_ & 3) * 8,    \
           (DSTH) + wave * 1024 + 512);                                   \
} while (0)

template <class Epi, bool SWZ>
__global__ __launch_bounds__(256, 3) void gemm3s(
    const bf16* __restrict__ A, const bf16* __restrict__ B,
    int lda, int ldb, int K, Epi epi)
{
  __shared__ bf16 smem[3][2][4096];   // [slot][A,B][128*32] = 48 KiB

  int bx = blockIdx.x, by = blockIdx.y;
  if constexpr (SWZ) {
    const int nbx = gridDim.x, nby = gridDim.y, nwg = nbx * nby;
    int bid = by * nbx + bx;
    const int q = nwg >> 3, r = nwg & 7;
    const int xcd = bid & 7, lid = bid >> 3;
    bid = (xcd < r ? xcd * (q + 1) : r * (q + 1) + (xcd - r) * q) + lid;
    const int gm = 8;
    const int pig = gm * nby;
    const int grp = bid / pig;
    const int fm = grp * gm;
    const int szm = min(nbx - fm, gm);
    const int loc = bid - grp * pig;
    bx = fm + loc % szm;
    by = loc / szm;
  }

  const int tid  = threadIdx.x;
  const int lane = tid & 63, wave = tid >> 6;
  const int wr = wave >> 1, wc = wave & 1;     // wave tile: 2M x 2N, 64x64
  const int lrow = lane & 15, quad = lane >> 4;
  // lane-constant swizzled byte offset within a 16-row fragment block
  const int lbase = (lrow >> 1) * 128 +
                    (((((lrow & 1) << 2) | quad) ^ ((lrow >> 1) & 7)) * 16);

  const bf16* gA = A + (long)(bx * 128) * lda;
  const bf16* gB = B + (long)(by * 128) * ldb;

  f32x4 acc[4][4] = {};
  bf16x8 af[4], bf_[4];

  const int NT = K >> 5;   // K-windows of 32

  // prologue: fully stage tiles 0,1 (8 loads/lane)
  STG2(gA, lda, 0, &smem[0][0][0]);
  STG2(gB, ldb, 0, &smem[0][1][0]);
  STG2(gA, lda, 1, &smem[1][0][0]);
  STG2(gB, ldb, 1, &smem[1][1][0]);
  asm volatile("s_waitcnt vmcnt(4)" ::: "memory");   // tile 0 retired
  __builtin_amdgcn_s_barrier();
  __builtin_amdgcn_sched_barrier(0);

  int st = 0, sp = 2;
  for (int t = 0; t < NT; ++t) {
    const bf16* aBuf = &smem[st][0][0];
    const bf16* bBuf = &smem[st][1][0];

    // ---- fragment reads + next staging up front ----
#pragma unroll
    for (int mi = 0; mi < 4; ++mi)
      af[mi] = *(const bf16x8*)((const char*)aBuf + (wr * 4 + mi) * 1024 + lbase);
#pragma unroll
    for (int ni = 0; ni < 4; ++ni)
      bf_[ni] = *(const bf16x8*)((const char*)bBuf + (wc * 4 + ni) * 1024 + lbase);
    if (t + 2 < NT) {
      STG2(gA, lda, t + 2, &smem[sp][0][0]);
      STG2(gB, ldb, t + 2, &smem[sp][1][0]);
    }

    // ---- MFMA cluster (compiler inserts fine-grained lgkmcnt) ----
    __builtin_amdgcn_s_setprio(1);
#pragma unroll
    for (int mi = 0; mi < 4; ++mi)
#pragma unroll
      for (int ni = 0; ni < 4; ++ni)
        acc[mi][ni] = __builtin_amdgcn_mfma_f32_16x16x32_bf16(
            af[mi], bf_[ni], acc[mi][ni], 0, 0, 0);
    __builtin_amdgcn_s_setprio(0);

    // ---- window end: pin staging above the counted drain, one barrier ----
    __builtin_amdgcn_sched_barrier(0);
    if (t + 2 < NT)      asm volatile("s_waitcnt vmcnt(4)" ::: "memory");
    else if (t + 1 < NT) asm volatile("s_waitcnt vmcnt(0)" ::: "memory");
    if (t + 1 < NT) {
      __builtin_amdgcn_s_barrier();
      __builtin_amdgcn_sched_barrier(0);
    }
    st = (st == 2) ? 0 : st + 1;
    sp = (sp == 2) ? 0 : sp + 1;
  }

  // C/D layout per 16x16 frag: col = lane&15, row = quad*4 + j  [m89/m91]
  const int rowbase = bx * 128 + wr * 64 + quad * 4;
  const int colbase = by * 128 + wc * 64 + lrow;
#pragma unroll
  for (int mi = 0; mi < 4; mi++)
#pragma unroll
    for (int ni = 0; ni < 4; ni++)
      epi(rowbase + mi * 16, colbase + ni * 16, 0, 0, acc[mi][ni]);
}

// ---------------- generic MFMA GEMM (m97 structure, 128x128) ----------------
#define BM 128
#define BN 128
#define BK 32

template <class Epi, bool DUAL, bool SWZ = false>
__global__ __launch_bounds__(256) void gemm_bt(
    const bf16* __restrict__ A, const bf16* __restrict__ B,
    int lda, int ldb, int K,
    long sAb, long sAg, long sBb, long sBg,
    const bf16* __restrict__ A2, const bf16* __restrict__ B2,
    int lda2, int ldb2, int K2,
    long sA2b, long sA2g, long sB2b, long sB2g,
    int gdiv, Epi epi)
{
  __shared__ bf16 As[BM * BK];
  __shared__ bf16 Bs[BN * BK];
  const int z = blockIdx.z;
  const int bb = z / gdiv, gg = z % gdiv;

  int bx = blockIdx.x, by = blockIdx.y;
  if constexpr (SWZ) {
    const int nbx = gridDim.x, nby = gridDim.y, nwg = nbx * nby;
    int bid = by * nbx + bx;
    const int q = nwg >> 3, r = nwg & 7;
    const int xcd = bid & 7, lid = bid >> 3;
    bid = (xcd < r ? xcd * (q + 1) : r * (q + 1) + (xcd - r) * q) + lid;
    const int gm = 8;
    const int pig = gm * nby;
    const int grp = bid / pig;
    const int fm = grp * gm;
    const int szm = min(nbx - fm, gm);
    const int loc = bid - grp * pig;
    bx = fm + loc % szm;
    by = loc / szm;
  }

  const int tid  = threadIdx.x;
  const int lane = tid & 63, wave = tid >> 6;
  const int wm = (wave >> 1) * 64, wn = (wave & 1) * 64;
  const int lrow = lane & 15, quad = lane >> 4;
  const int srow = wave * 16 + (lane >> 2);
  const int scol = (lane & 3) * 8;
  bf16* ldsA0 = As + wave * 512;
  bf16* ldsA1 = As + (wave + 4) * 512;
  bf16* ldsB0 = Bs + wave * 512;
  bf16* ldsB1 = Bs + (wave + 4) * 512;

  f32x4 acc[4][4] = {};

  auto kloop = [&](const bf16* __restrict__ Ab, const bf16* __restrict__ Bb,
                   int lda_, int ldb_, int K_) {
    for (int k0 = 0; k0 < K_; k0 += BK) {
      __syncthreads();
      gl_lds16(Ab + (long)srow * lda_ + k0 + scol,        ldsA0);
      gl_lds16(Ab + (long)(srow + 64) * lda_ + k0 + scol, ldsA1);
      gl_lds16(Bb + (long)srow * ldb_ + k0 + scol,        ldsB0);
      gl_lds16(Bb + (long)(srow + 64) * ldb_ + k0 + scol, ldsB1);
      __syncthreads();
      bf16x8 af[4], bfr[4];
#pragma unroll
      for (int i = 0; i < 4; i++) af[i]  = *(const bf16x8*)&As[(wm + i * 16 + lrow) * BK + quad * 8];
#pragma unroll
      for (int i = 0; i < 4; i++) bfr[i] = *(const bf16x8*)&Bs[(wn + i * 16 + lrow) * BK + quad * 8];
#pragma unroll
      for (int mi = 0; mi < 4; mi++)
#pragma unroll
        for (int ni = 0; ni < 4; ni++)
          acc[mi][ni] = __builtin_amdgcn_mfma_f32_16x16x32_bf16(af[mi], bfr[ni], acc[mi][ni], 0, 0, 0);
    }
  };

  kloop(A + (long)bb * sAb + (long)gg * sAg + (long)bx * BM * lda,
        B + (long)bb * sBb + (long)gg * sBg + (long)by * BN * ldb, lda, ldb, K);
  if constexpr (DUAL)
    kloop(A2 + (long)bb * sA2b + (long)gg * sA2g + (long)bx * BM * lda2,
          B2 + (long)bb * sB2b + (long)gg * sB2g + (long)by * BN * ldb2, lda2, ldb2, K2);

  const int rowbase = bx * BM + wm + quad * 4;
  const int colbase = by * BN + wn + lrow;
#pragma unroll
  for (int mi = 0; mi < 4; mi++)
#pragma unroll
    for (int ni = 0; ni < 4; ni++)
      epi(rowbase + mi * 16, colbase + ni * 16, bb, gg, acc[mi][ni]);
}

// ---------------- epilogues (a[j] belongs to row row0+j, fixed col) ----------------
struct EpiGemm1 {   // silu(x@W1 + b1) -> u, v (direct into vT layout)
  const float* b1; bf16* u; bf16* vT; bf16* z;
  __device__ void operator()(int row0, int col, int, int, f32x4 a) const {
    float s[4];
    const float bias = b1[col];
#pragma unroll
    for (int j = 0; j < 4; j++) {
      float x = a[j] + bias;
      float e = __expf(-x);
      s[j] = __fdividef(x, 1.f + e);
    }
    if (col < E_) {
#pragma unroll
      for (int j = 0; j < 4; j++) u[(long)(row0 + j) * E_ + col] = (bf16)s[j];
    } else if (col < 2 * E_) {
      const int e = col - E_, b = row0 >> 12, t = row0 & 4095;
      bf16x4 o;
#pragma unroll
      for (int j = 0; j < 4; j++) o[j] = (bf16)s[j];
      *(bf16x4*)&vT[((long)(b * E_ + e)) * 4096 + t] = o;
    } else {
      const int sc = col - 2 * E_;
#pragma unroll
      for (int j = 0; j < 4; j++) z[(long)(row0 + j) * S_ + sc] = (bf16)s[j];
    }
  }
};
struct EpiZ {   // silu(x@W1[:,2E:] + b1[2E+col]) -> z
  const float* b1; bf16* z;
  __device__ void operator()(int row0, int col, int, int, f32x4 a) const {
    const float bias = b1[2 * E_ + col];
#pragma unroll
    for (int j = 0; j < 4; j++) {
      float x = a[j] + bias;
      float e = __expf(-x);
      z[(long)(row0 + j) * S_ + col] = (bf16)__fdividef(x, 1.f + e);
    }
  }
};
struct EpiF32 {
  float* C; long sCb, sCg; int ldc;
  __device__ void operator()(int row0, int col, int bb, int gg, f32x4 a) const {
#pragma unroll
    for (int j = 0; j < 4; j++)
      C[(long)bb * sCb + (long)gg * sCg + (long)(row0 + j) * ldc + col] = a[j];
  }
};
struct EpiBf16 {
  bf16* C; long sCb, sCg; int ldc;
  __device__ void operator()(int row0, int col, int bb, int gg, f32x4 a) const {
#pragma unroll
    for (int j = 0; j < 4; j++)
      C[(long)bb * sCb + (long)gg * sCg + (long)(row0 + j) * ldc + col] = (bf16)a[j];
  }
};
struct EpiKer {   // relu(qk/n + w_rel[511+col-row])^2
  bf16* C; const float* wrel;
  __device__ void operator()(int row0, int col, int bb, int, f32x4 a) const {
#pragma unroll
    for (int j = 0; j < 4; j++) {
      float v = a[j] * (1.f / 256.f) + wrel[511 + col - (row0 + j)];
      v = fmaxf(v, 0.f);
      C[(long)bb * 65536 + (long)(row0 + j) * 256 + col] = (bf16)(v * v);
    }
  }
};
struct EpiCombine {   // P = u * (quadratic + linear), in-place over u
  bf16* u;
  __device__ void operator()(int row0, int col, int bb, int gg, f32x4 a) const {
#pragma unroll
    for (int j = 0; j < 4; j++) {
      long idx = ((long)((bb * 16 + gg) * 256 + row0 + j)) * E_ + col;
      u[idx] = (bf16)((float)u[idx] * a[j]);
    }
  }
};
struct EpiFinal {   // out = P@W2 + b2 + shortcut
  float* out; const float* b2; const float* x0;
  __device__ void operator()(int row0, int col, int, int, f32x4 a) const {
#pragma unroll
    for (int j = 0; j < 4; j++) {
      long idx = (long)(row0 + j) * D_ + col;
      out[idx] = a[j] + b2[col] + x0[idx];
    }
  }
};

// ---------------- LayerNorm -> bf16 ----------------
__global__ __launch_bounds__(256) void ln_kernel(
    const float* __restrict__ x, const float* __restrict__ w,
    const float* __restrict__ b, bf16* __restrict__ xn)
{
  const long t = blockIdx.x;
  const float* row = x + t * D_;
  const int tid = threadIdx.x;
  float v0 = row[tid], v1 = row[tid + 256], v2 = row[tid + 512];
  float s = v0 + v1 + v2;
  float sq = v0 * v0 + v1 * v1 + v2 * v2;
#pragma unroll
  for (int off = 32; off; off >>= 1) {
    s  += __shfl_down(s, off, 64);
    sq += __shfl_down(sq, off, 64);
  }
  __shared__ float red[2][4];
  const int wave = tid >> 6, lane = tid & 63;
  if (lane == 0) { red[0][wave] = s; red[1][wave] = sq; }
  __syncthreads();
  s  = red[0][0] + red[0][1] + red[0][2] + red[0][3];
  sq = red[1][0] + red[1][1] + red[1][2] + red[1][3];
  const float mean = s * (1.f / 768.f);
  const float var  = sq * (1.f / 768.f) - mean * mean;
  const float rs   = rsqrtf(var + 1e-5f);
  xn[t * D_ + tid]       = (bf16)((v0 - mean) * rs * w[tid] + b[tid]);
  xn[t * D_ + tid + 256] = (bf16)((v1 - mean) * rs * w[tid + 256] + b[tid + 256]);
  xn[t * D_ + tid + 512] = (bf16)((v2 - mean) * rs * w[tid + 512] + b[tid + 512]);
}

// ---------------- tiled transpose + cast to bf16 ----------------
template <class TI>
__global__ __launch_bounds__(256) void transpose_cast(
    const TI* __restrict__ in, bf16* __restrict__ out,
    int R, int C, long sInB, long sOutB)
{
  __shared__ float tile[64][65];
  const TI* ib = in  + (long)blockIdx.z * sInB;
  bf16*     ob = out + (long)blockIdx.z * sOutB;
  const int c0 = blockIdx.x * 64, r0 = blockIdx.y * 64;
  const int lc = threadIdx.x & 63, lr0 = threadIdx.x >> 6;
#pragma unroll
  for (int i = 0; i < 16; i++) {
    int r = lr0 + i * 4;
    tile[r][lc] = (float)ib[(long)(r0 + r) * C + c0 + lc];
  }
  __syncthreads();
#pragma unroll
  for (int i = 0; i < 16; i++) {
    int r = lr0 + i * 4;
    ob[(long)(c0 + r) * R + r0 + lc] = (bf16)tile[lc][r];
  }
}

// ---------------- RoPE sin/cos table ----------------
__global__ __launch_bounds__(256) void rope_table_kernel(
    const float* __restrict__ invf, float2* __restrict__ tab)
{
  int idx = blockIdx.x * 256 + threadIdx.x;   // 4096*64 entries
  int p = idx >> 6, i = idx & 63;
  float arg = (float)p * invf[i];
  double a = (double)arg;
  tab[idx] = make_float2((float)sin(a), (float)cos(a));
}

// ---------------- z -> gamma/beta -> rope -> 4 gate rows ----------------
__global__ __launch_bounds__(128) void rope_kernel(
    const bf16* __restrict__ zbuf, const float* __restrict__ gamma,
    const float* __restrict__ beta, const float2* __restrict__ tab,
    bf16* __restrict__ qq, bf16* __restrict__ qk,
    bf16* __restrict__ lq, bf16* __restrict__ lk)
{
  const long t = blockIdx.x;
  const int s = threadIdx.x;
  const int p = (int)(t & 4095);
  const int i = s & 63;
  const float2 sc = tab[p * 64 + i];
  const bf16* zr = zbuf + t * S_;
  const float zlo = (float)zr[i], zhi = (float)zr[i + 64];
  bf16* outs[4] = {qq, qk, lq, lk};
#pragma unroll
  for (int r = 0; r < 4; r++) {
    float zl = zlo * gamma[r * 128 + i]      + beta[r * 128 + i];
    float zh = zhi * gamma[r * 128 + i + 64] + beta[r * 128 + i + 64];
    float val = (s < 64) ? (zl * sc.y - zh * sc.x) : (zh * sc.y + zl * sc.x);
    outs[r][t * S_ + s] = (bf16)val;
  }
}

// ---------------- segment mask ----------------
__global__ __launch_bounds__(64) void mask_kernel(const int* __restrict__ seg, float* __restrict__ mask) {
  __shared__ int mn[16], mx[16];
  const int b = blockIdx.x, tid = threadIdx.x;
  if (tid < 16) {
    const int* p = seg + (long)b * 4096 + tid * 256;
    int lo = p[0], hi = p[0];
    for (int i = 1; i < 256; i++) { int v = p[i]; lo = min(lo, v); hi = max(hi, v); }
    mn[tid] = lo; mx[tid] = hi;
  }
  __syncthreads();
  if (tid < 16) {
    const int g = tid;
    float row[16]; float s = 0.f;
    for (int h = 0; h < 16; h++) {
      float o = (mn[g] <= mx[h] && mx[g] >= mn[h]) ? 1.f : 0.f;
      row[h] = o; s += o;
    }
    const float inv = 1.f / s;
    for (int h = 0; h < 16; h++) mask[((long)b * 16 + g) * 16 + h] = row[h] * inv;
  }
}

// ---------------- mask-mix of P2 (folds 1/n) ----------------
__global__ __launch_bounds__(256) void mix_kernel(
    const float* __restrict__ P2, const float* __restrict__ mask, bf16* __restrict__ amix)
{
  const int z = blockIdx.x;          // b*16 + g
  const int b = z >> 4;
  float m[16];
#pragma unroll
  for (int h = 0; h < 16; h++) m[h] = mask[(long)z * 16 + h] * (1.f / 256.f);
  const float* Pb = P2 + (long)b * 16 * 16384;
  bf16* Ab = amix + (long)z * 16384;
#pragma unroll 4
  for (int j = 0; j < 16; j++) {
    int c = j * 256 + threadIdx.x;
    float ax = 0, ay = 0, az = 0, aw = 0;
#pragma unroll
    for (int h = 0; h < 16; h++) {
      float4 p = ((const float4*)(Pb + (long)h * 16384))[c];
      ax += m[h] * p.x; ay += m[h] * p.y; az += m[h] * p.z; aw += m[h] * p.w;
    }
    bf16x4 o; o[0] = (bf16)ax; o[1] = (bf16)ay; o[2] = (bf16)az; o[3] = (bf16)aw;
    *(bf16x4*)&Ab[(long)c * 4] = o;
  }
}

// ---------------- launch ----------------
extern "C" void kernel_launch(void* const* d_in, const int* in_sizes, int n_in,
                              void* d_out, int out_size, void* d_ws, size_t ws_size,
                              hipStream_t stream)
{
  const float* x0    = (const float*)d_in[0];
  const int*   seg   = (const int*)d_in[1];
  const float* lnw   = (const float*)d_in[2];
  const float* lnb   = (const float*)d_in[3];
  const float* W1    = (const float*)d_in[4];
  const float* b1    = (const float*)d_in[5];
  const float* gamma = (const float*)d_in[6];
  const float* beta  = (const float*)d_in[7];
  const float* W2    = (const float*)d_in[8];
  const float* b2    = (const float*)d_in[9];
  const float* wrel  = (const float*)d_in[10];
  float* out = (float*)d_out;
  char* ws = (char*)d_ws;

  bf16*   w1t   = (bf16*)(ws + OFF_W1T);
  bf16*   w2t   = (bf16*)(ws + OFF_W2T);
  float2* tab   = (float2*)(ws + OFF_TAB);
  bf16*   xn    = (bf16*)(ws + OFF_XN);
  bf16*   ker   = (bf16*)(ws + OFF_KER);
  bf16*   qq    = (bf16*)(ws + OFF_QQ);
  bf16*   qk    = (bf16*)(ws + OFF_QK);
  bf16*   lq    = (bf16*)(ws + OFF_LQ);
  bf16*   u     = (bf16*)(ws + OFF_U);
  bf16*   zb    = (bf16*)(ws + OFF_Z);
  float*  P2    = (float*)(ws + OFF_Z);
  bf16*   lk    = (bf16*)(ws + OFF_LK);
  bf16*   T1    = (bf16*)(ws + OFF_LK);
  bf16*   lqT   = (bf16*)(ws + OFF_LQT);
  bf16*   amix  = (bf16*)(ws + OFF_LQT);
  bf16*   kvT   = (bf16*)(ws + OFF_LQT + 4194304UL);
  bf16*   lkT   = (bf16*)(ws + OFF_LKT);
  float*  maskb = (float*)(ws + OFF_MASK);
  float*  invfd = (float*)(ws + OFF_INVF);
  bf16*   vTd   = (bf16*)d_out;

  static float h_invf[64];
  for (int i = 0; i < 64; i++) h_invf[i] = powf(10000.0f, (float)i * (1.0f / 64.0f));
  hipMemcpyAsync(invfd, h_invf, 64 * sizeof(float), hipMemcpyHostToDevice, stream);

  // prep (independent)
  transpose_cast<float><<<dim3(50, 12, 1), 256, 0, stream>>>(W1, w1t, 768, 3200, 0, 0);
  transpose_cast<float><<<dim3(12, 24, 1), 256, 0, stream>>>(W2, w2t, 1536, 768, 0, 0);
  rope_table_kernel<<<1024, 256, 0, stream>>>(invfd, tab);
  mask_kernel<<<8, 64, 0, stream>>>(seg, maskb);

  // LN -> xn (bf16)
  ln_kernel<<<TT_, 256, 0, stream>>>(x0, lnw, lnb, xn);

  // GEMM1 (u,v cols 0..3071): 3-slot pipelined 128^2, 3 blocks/CU
  gemm3s<EpiGemm1, true><<<dim3(256, 24), 256, 0, stream>>>(
      xn, w1t, 768, 768, 768, EpiGemm1{b1, u, vTd, zb});
  // GEMM1 z-slice (cols 3072..3199): 128^2 pass
  gemm_bt<EpiZ, false><<<dim3(256, 1, 1), 256, 0, stream>>>(
      xn, w1t + (long)3072 * 768, 768, 768, 768, 0, 0, 0, 0,
      nullptr, nullptr, 0, 0, 0, 0, 0, 0, 0, 1, EpiZ{b1, zb});

  // z -> 4 rope'd gate rows
  rope_kernel<<<TT_, 128, 0, stream>>>(zb, gamma, beta, tab, qq, qk, lq, lk);

  // lq/lk -> transposed (per b: 4096x128 -> 128x4096)
  transpose_cast<bf16><<<dim3(2, 64, 8), 256, 0, stream>>>(lq, lqT, 4096, 128, 524288, 524288);
  transpose_cast<bf16><<<dim3(2, 64, 8), 256, 0, stream>>>(lk, lkT, 4096, 128, 524288, 524288);

  // P2[b,h][s][k] = sum_c lq[c][s] lk[c][k]
  gemm_bt<EpiF32, false><<<dim3(1, 1, 128), 256, 0, stream>>>(
      lqT, lkT, 4096, 4096, 256, 524288, 256, 524288, 256,
      nullptr, nullptr, 0, 0, 0, 0, 0, 0, 0, 16, EpiF32{P2, 262144, 16384, 128});

  // amix[b,g] = sum_h mask/n * P2[b,h]
  mix_kernel<<<128, 256, 0, stream>>>(P2, maskb, amix);

  // kvT[b][e][s] = sum_t v[t][e] lk[t][s]
  gemm_bt<EpiBf16, false><<<dim3(12, 1, 8), 256, 0, stream>>>(
      vTd, lkT, 4096, 4096, 4096, 6291456, 0, 524288, 0,
      nullptr, nullptr, 0, 0, 0, 0, 0, 0, 0, 1, EpiBf16{kvT, 196608, 0, 128});

  // T1[t][s] = sum_k lq[t][k] amix[b,g][s][k]
  gemm_bt<EpiBf16, false><<<dim3(2, 1, 128), 256, 0, stream>>>(
      lq, amix, 128, 128, 128, 32768, 0, 16384, 0,
      nullptr, nullptr, 0, 0, 0, 0, 0, 0, 0, 1, EpiBf16{T1, 32768, 0, 128});

  // ker[b,g][n][m] = relu(qq.qk/n + bias)^2
  gemm_bt<EpiKer, false><<<dim3(2, 2, 128), 256, 0, stream>>>(
      qq, qk, 128, 128, 128, 32768, 0, 32768, 0,
      nullptr, nullptr, 0, 0, 0, 0, 0, 0, 0, 1, EpiKer{ker, wrel});

  // combine (dual-K): P = u * (ker@v + T1@kv), in-place over u
  gemm_bt<EpiCombine, true><<<dim3(2, 12, 128), 256, 0, stream>>>(
      ker, vTd, 256, 4096, 256, 1048576, 65536, 6291456, 256,
      T1, kvT, 128, 128, 128, 524288, 32768, 196608, 0, 16, EpiCombine{u});

  // out = P@W2 + b2 + shortcut: 3-slot pipelined 128^2
  gemm3s<EpiFinal, true><<<dim3(256, 6), 256, 0, stream>>>(
      u, w2t, 1536, 1536, 1536, EpiFinal{out, b2, x0});
}

// Round 6
// 858.463 us; speedup vs baseline: 1.2864x; 1.0981x over previous
//
#include <hip/hip_runtime.h>
#include <math.h>

typedef __bf16 bf16;
typedef __bf16 bf16x8 __attribute__((ext_vector_type(8)));
typedef __bf16 bf16x4 __attribute__((ext_vector_type(4)));
typedef float  f32x4  __attribute__((ext_vector_type(4)));

// Problem constants
#define D_   768
#define E_   1536
#define S_   128
#define TT_  32768     // B*G*N tokens
#define B_   8

// ---------------- workspace layout (bytes) ----------------
#define OFF_W1T   0UL                       // 3200x768 bf16  = 4,915,200
#define OFF_W2T   4915200UL                 // 768x1536 bf16  = 2,359,296
#define OFF_TAB   7274496UL                 // 4096x64 float2 = 2,097,152
#define OFF_XN    9375744UL                 // 32768x768 bf16 = 50,331,648
#define OFF_KER   OFF_XN                    //   reuse: 128x256x256 bf16 = 16,777,216
#define OFF_QQ    (OFF_XN + 16777216UL)     //   reuse: 32768x128 bf16 = 8,388,608 ; later kv4 (12.6M)
#define OFF_QK    (OFF_XN + 25165824UL)     //   reuse: 8,388,608
#define OFF_LQ    (OFF_XN + 33554432UL)     //   reuse: 8,388,608 (ends XN+41.9M < 50.3M)
#define OFF_U     59707392UL                // 32768x1536 bf16 = 100,663,296 (combine in-place -> P)
#define OFF_Z     160370688UL               // 32768x128 bf16 ; reuse: P2 f32 (same 8,388,608 bytes)
#define OFF_LK    168759296UL               // 8,388,608 ; reuse: T1
#define OFF_LQT   177147904UL               // 8,388,608 ; reuse: amix (4,194,304) + kvT (3,145,728)
#define OFF_LKT   185536512UL               // 8,388,608
#define OFF_MASK  193925120UL               // 8x16x16 f32 = 8,192 (FULL size)
#define OFF_INVF  193933312UL               // 64 f32 -> end 193,933,568 (~185 MiB)

// ---------------- async global->LDS staging ----------------
// HW: per-lane global gather, LDS dest = wave-uniform base + lane*16.
__device__ __forceinline__ void gl_lds16(const bf16* g, bf16* l) {
  __builtin_amdgcn_global_load_lds(
      (const __attribute__((address_space(1))) unsigned int*)g,
      (__attribute__((address_space(3))) unsigned int*)l, 16, 0, 0);
}

// =================================================================
// 128x128 pipelined GEMM, 3-slot LDS rotation, 3 blocks/CU.
// C[M,N] = A[M,K] * B[N,K]^T (+ optional second A2*B2^T accumulated);
// M%128==0, N%128==0, K%32==0, K>=64.
// 256 threads = 4 waves (2M x 2N), per-wave output 64x64 (acc=64 AGPR).
// K-window = 32. LDS: 3 slots x {A,B} halves of 128x32 bf16 (8 KB each)
// = 48 KiB -> 3 blocks/CU. Window t reads slot t%3 (read-only) and
// stages tile t+2 into slot (t+2)%3 (its last readers finished at the
// end-of-(t-1) barrier -> WAR-safe). End of window: sched_barrier(0)
// pins staging above the counted vmcnt(4) (drains tile t+1, leaves
// t+2 in flight -> RAW-safe); ONE s_barrier per window. For DUAL, a
// __syncthreads() before the 2nd kloop protects slots 0/1 from
// stragglers of kloop1's final window. Cross-block overlap (3/CU)
// hides prologue fill + epilogue stores.
// LDS layout (per half): line j (128 B) holds rows {2j,2j+1}; 16B slot
// s of line j holds logical chunk s^(j&7), chunk c = (row&1)*4 + quad.
// Stage pre-swizzles the GLOBAL gather address (LDS dest stays linear);
// fragment reads hit all 8 banksets -> conflict-free ds_read_b128.
// =================================================================

// stage rows [wave*32, wave*32+32) of a 128-row half (2 loads/wave)
#define STG2(GB, LD, KT, DSTH) do {                                       \
  const int cg_ = (lane & 7) ^ ((lane >> 3) & 7);                         \
  const int rg_ = wave * 32 + ((lane >> 3) << 1) + (cg_ >> 2);            \
  gl_lds16((GB) + (long)rg_ * (LD) + (KT) * 32 + (cg_ & 3) * 8,           \
           (DSTH) + wave * 1024);                                         \
  gl_lds16((GB) + (long)(rg_ + 16) * (LD) + (KT) * 32 + (cg_ & 3) * 8,    \
           (DSTH) + wave * 1024 + 512);                                   \
} while (0)

template <class Epi, bool DUAL, bool SWZ>
__global__ __launch_bounds__(256, 3) void gemm3s(
    const bf16* __restrict__ A, const bf16* __restrict__ B,
    int lda, int ldb, int K,
    long sAb, long sAg, long sBb, long sBg,
    const bf16* __restrict__ A2, const bf16* __restrict__ B2,
    int lda2, int ldb2, int K2,
    long sA2b, long sA2g, long sB2b, long sB2g,
    int gdiv, Epi epi)
{
  __shared__ bf16 smem[3][2][4096];   // [slot][A,B][128*32] = 48 KiB

  const int z = blockIdx.z;
  const int bb = z / gdiv, gg = z % gdiv;

  int bx = blockIdx.x, by = blockIdx.y;
  if constexpr (SWZ) {
    const int nbx = gridDim.x, nby = gridDim.y, nwg = nbx * nby;
    int bid = by * nbx + bx;
    const int q = nwg >> 3, r = nwg & 7;
    const int xcd = bid & 7, lid = bid >> 3;
    bid = (xcd < r ? xcd * (q + 1) : r * (q + 1) + (xcd - r) * q) + lid;
    const int gm = 8;
    const int pig = gm * nby;
    const int grp = bid / pig;
    const int fm = grp * gm;
    const int szm = min(nbx - fm, gm);
    const int loc = bid - grp * pig;
    bx = fm + loc % szm;
    by = loc / szm;
  }

  const int tid  = threadIdx.x;
  const int lane = tid & 63, wave = tid >> 6;
  const int wr = wave >> 1, wc = wave & 1;     // wave tile: 2M x 2N, 64x64
  const int lrow = lane & 15, quad = lane >> 4;
  // lane-constant swizzled byte offset within a 16-row fragment block
  const int lbase = (lrow >> 1) * 128 +
                    (((((lrow & 1) << 2) | quad) ^ ((lrow >> 1) & 7)) * 16);

  f32x4 acc[4][4] = {};
  bf16x8 af[4], bf_[4];

  auto run = [&](const bf16* __restrict__ gA, const bf16* __restrict__ gB,
                 int lda_, int ldb_, int K_, bool first) {
    const int NT = K_ >> 5;   // K-windows of 32
    if (!first) __syncthreads();   // protect slots from prev kloop's readers
    // prologue: fully stage tiles 0,1 (8 loads/lane)
    STG2(gA, lda_, 0, &smem[0][0][0]);
    STG2(gB, ldb_, 0, &smem[0][1][0]);
    STG2(gA, lda_, 1, &smem[1][0][0]);
    STG2(gB, ldb_, 1, &smem[1][1][0]);
    asm volatile("s_waitcnt vmcnt(4)" ::: "memory");   // tile 0 retired
    __builtin_amdgcn_s_barrier();
    __builtin_amdgcn_sched_barrier(0);

    int st = 0, sp = 2;
    for (int t = 0; t < NT; ++t) {
      const bf16* aBuf = &smem[st][0][0];
      const bf16* bBuf = &smem[st][1][0];

      // ---- fragment reads + next staging up front ----
#pragma unroll
      for (int mi = 0; mi < 4; ++mi)
        af[mi] = *(const bf16x8*)((const char*)aBuf + (wr * 4 + mi) * 1024 + lbase);
#pragma unroll
      for (int ni = 0; ni < 4; ++ni)
        bf_[ni] = *(const bf16x8*)((const char*)bBuf + (wc * 4 + ni) * 1024 + lbase);
      if (t + 2 < NT) {
        STG2(gA, lda_, t + 2, &smem[sp][0][0]);
        STG2(gB, ldb_, t + 2, &smem[sp][1][0]);
      }

      // ---- MFMA cluster (compiler inserts fine-grained lgkmcnt) ----
      __builtin_amdgcn_s_setprio(1);
#pragma unroll
      for (int mi = 0; mi < 4; ++mi)
#pragma unroll
        for (int ni = 0; ni < 4; ++ni)
          acc[mi][ni] = __builtin_amdgcn_mfma_f32_16x16x32_bf16(
              af[mi], bf_[ni], acc[mi][ni], 0, 0, 0);
      __builtin_amdgcn_s_setprio(0);

      // ---- window end: pin staging above the counted drain, one barrier ----
      __builtin_amdgcn_sched_barrier(0);
      if (t + 2 < NT)      asm volatile("s_waitcnt vmcnt(4)" ::: "memory");
      else if (t + 1 < NT) asm volatile("s_waitcnt vmcnt(0)" ::: "memory");
      if (t + 1 < NT) {
        __builtin_amdgcn_s_barrier();
        __builtin_amdgcn_sched_barrier(0);
      }
      st = (st == 2) ? 0 : st + 1;
      sp = (sp == 2) ? 0 : sp + 1;
    }
  };

  run(A + bb * sAb + gg * sAg + (long)bx * 128 * lda,
      B + bb * sBb + gg * sBg + (long)by * 128 * ldb, lda, ldb, K, true);
  if constexpr (DUAL)
    run(A2 + bb * sA2b + gg * sA2g + (long)bx * 128 * lda2,
        B2 + bb * sB2b + gg * sB2g + (long)by * 128 * ldb2, lda2, ldb2, K2, false);

  // C/D layout per 16x16 frag: col = lane&15, row = quad*4 + j  [m89/m91]
  const int rowbase = bx * 128 + wr * 64 + quad * 4;
  const int colbase = by * 128 + wc * 64 + lrow;
#pragma unroll
  for (int mi = 0; mi < 4; mi++)
#pragma unroll
    for (int ni = 0; ni < 4; ni++)
      epi(rowbase + mi * 16, colbase + ni * 16, bb, gg, acc[mi][ni]);
}

// ---------------- epilogues (a[j] belongs to row row0+j, fixed col) ----------------
struct EpiGemm1 {   // silu(x@W1 + b1) -> u, v (direct into vT layout), z
  const float* b1; bf16* u; bf16* vT; bf16* z;
  __device__ void operator()(int row0, int col, int, int, f32x4 a) const {
    float s[4];
    const float bias = b1[col];
#pragma unroll
    for (int j = 0; j < 4; j++) {
      float x = a[j] + bias;
      float e = __expf(-x);
      s[j] = __fdividef(x, 1.f + e);
    }
    if (col < E_) {
#pragma unroll
      for (int j = 0; j < 4; j++) u[(long)(row0 + j) * E_ + col] = (bf16)s[j];
    } else if (col < 2 * E_) {
      const int e = col - E_, b = row0 >> 12, t = row0 & 4095;
      bf16x4 o;
#pragma unroll
      for (int j = 0; j < 4; j++) o[j] = (bf16)s[j];
      *(bf16x4*)&vT[((long)(b * E_ + e)) * 4096 + t] = o;
    } else {
      const int sc = col - 2 * E_;
#pragma unroll
      for (int j = 0; j < 4; j++) z[(long)(row0 + j) * S_ + sc] = (bf16)s[j];
    }
  }
};
struct EpiF32 {
  float* C; long sCb, sCg; int ldc;
  __device__ void operator()(int row0, int col, int bb, int gg, f32x4 a) const {
#pragma unroll
    for (int j = 0; j < 4; j++)
      C[(long)bb * sCb + (long)gg * sCg + (long)(row0 + j) * ldc + col] = a[j];
  }
};
struct EpiBf16 {
  bf16* C; long sCb, sCg; int ldc;
  __device__ void operator()(int row0, int col, int bb, int gg, f32x4 a) const {
#pragma unroll
    for (int j = 0; j < 4; j++)
      C[(long)bb * sCb + (long)gg * sCg + (long)(row0 + j) * ldc + col] = (bf16)a[j];
  }
};
struct EpiKer {   // relu(qk/n + w_rel[511+col-row])^2
  bf16* C; const float* wrel;
  __device__ void operator()(int row0, int col, int bb, int, f32x4 a) const {
#pragma unroll
    for (int j = 0; j < 4; j++) {
      float v = a[j] * (1.f / 256.f) + wrel[511 + col - (row0 + j)];
      v = fmaxf(v, 0.f);
      C[(long)bb * 65536 + (long)(row0 + j) * 256 + col] = (bf16)(v * v);
    }
  }
};
struct EpiCombine {   // P = u * (quadratic + linear), in-place over u
  bf16* u;
  __device__ void operator()(int row0, int col, int bb, int gg, f32x4 a) const {
#pragma unroll
    for (int j = 0; j < 4; j++) {
      long idx = ((long)((bb * 16 + gg) * 256 + row0 + j)) * E_ + col;
      u[idx] = (bf16)((float)u[idx] * a[j]);
    }
  }
};
struct EpiFinal {   // out = P@W2 + b2 + shortcut
  float* out; const float* b2; const float* x0;
  __device__ void operator()(int row0, int col, int, int, f32x4 a) const {
#pragma unroll
    for (int j = 0; j < 4; j++) {
      long idx = (long)(row0 + j) * D_ + col;
      out[idx] = a[j] + b2[col] + x0[idx];
    }
  }
};

// ---------------- kv split-K partial sum: kvT = sum_ks kv4[.., ks*128+s] ----------------
__global__ __launch_bounds__(256) void kvsum_kernel(
    const bf16* __restrict__ kv4, bf16* __restrict__ kvT)
{
  const long i = (long)blockIdx.x * 256 + threadIdx.x;   // 8*1536*128 = 1,572,864
  const int s = (int)(i & 127);
  const long esb = i >> 7;                               // b*1536 + e
  const bf16* p = kv4 + (esb << 9) + s;                  // [b][e][512]
  float v = (float)p[0] + (float)p[128] + (float)p[256] + (float)p[384];
  kvT[i] = (bf16)v;                                      // [b][e][128] flat == i
}

// ---------------- LayerNorm -> bf16 ----------------
__global__ __launch_bounds__(256) void ln_kernel(
    const float* __restrict__ x, const float* __restrict__ w,
    const float* __restrict__ b, bf16* __restrict__ xn)
{
  const long t = blockIdx.x;
  const float* row = x + t * D_;
  const int tid = threadIdx.x;
  float v0 = row[tid], v1 = row[tid + 256], v2 = row[tid + 512];
  float s = v0 + v1 + v2;
  float sq = v0 * v0 + v1 * v1 + v2 * v2;
#pragma unroll
  for (int off = 32; off; off >>= 1) {
    s  += __shfl_down(s, off, 64);
    sq += __shfl_down(sq, off, 64);
  }
  __shared__ float red[2][4];
  const int wave = tid >> 6, lane = tid & 63;
  if (lane == 0) { red[0][wave] = s; red[1][wave] = sq; }
  __syncthreads();
  s  = red[0][0] + red[0][1] + red[0][2] + red[0][3];
  sq = red[1][0] + red[1][1] + red[1][2] + red[1][3];
  const float mean = s * (1.f / 768.f);
  const float var  = sq * (1.f / 768.f) - mean * mean;
  const float rs   = rsqrtf(var + 1e-5f);
  xn[t * D_ + tid]       = (bf16)((v0 - mean) * rs * w[tid] + b[tid]);
  xn[t * D_ + tid + 256] = (bf16)((v1 - mean) * rs * w[tid + 256] + b[tid + 256]);
  xn[t * D_ + tid + 512] = (bf16)((v2 - mean) * rs * w[tid + 512] + b[tid + 512]);
}

// ---------------- tiled transpose + cast to bf16 ----------------
template <class TI>
__global__ __launch_bounds__(256) void transpose_cast(
    const TI* __restrict__ in, bf16* __restrict__ out,
    int R, int C, long sInB, long sOutB)
{
  __shared__ float tile[64][65];
  const TI* ib = in  + (long)blockIdx.z * sInB;
  bf16*     ob = out + (long)blockIdx.z * sOutB;
  const int c0 = blockIdx.x * 64, r0 = blockIdx.y * 64;
  const int lc = threadIdx.x & 63, lr0 = threadIdx.x >> 6;
#pragma unroll
  for (int i = 0; i < 16; i++) {
    int r = lr0 + i * 4;
    tile[r][lc] = (float)ib[(long)(r0 + r) * C + c0 + lc];
  }
  __syncthreads();
#pragma unroll
  for (int i = 0; i < 16; i++) {
    int r = lr0 + i * 4;
    ob[(long)(c0 + r) * R + r0 + lc] = (bf16)tile[lc][r];
  }
}

// ---------------- RoPE sin/cos table ----------------
__global__ __launch_bounds__(256) void rope_table_kernel(
    const float* __restrict__ invf, float2* __restrict__ tab)
{
  int idx = blockIdx.x * 256 + threadIdx.x;   // 4096*64 entries
  int p = idx >> 6, i = idx & 63;
  float arg = (float)p * invf[i];
  double a = (double)arg;
  tab[idx] = make_float2((float)sin(a), (float)cos(a));
}

// ---------------- z -> gamma/beta -> rope -> 4 gate rows ----------------
__global__ __launch_bounds__(128) void rope_kernel(
    const bf16* __restrict__ zbuf, const float* __restrict__ gamma,
    const float* __restrict__ beta, const float2* __restrict__ tab,
    bf16* __restrict__ qq, bf16* __restrict__ qk,
    bf16* __restrict__ lq, bf16* __restrict__ lk)
{
  const long t = blockIdx.x;
  const int s = threadIdx.x;
  const int p = (int)(t & 4095);
  const int i = s & 63;
  const float2 sc = tab[p * 64 + i];
  const bf16* zr = zbuf + t * S_;
  const float zlo = (float)zr[i], zhi = (float)zr[i + 64];
  bf16* outs[4] = {qq, qk, lq, lk};
#pragma unroll
  for (int r = 0; r < 4; r++) {
    float zl = zlo * gamma[r * 128 + i]      + beta[r * 128 + i];
    float zh = zhi * gamma[r * 128 + i + 64] + beta[r * 128 + i + 64];
    float val = (s < 64) ? (zl * sc.y - zh * sc.x) : (zh * sc.y + zl * sc.x);
    outs[r][t * S_ + s] = (bf16)val;
  }
}

// ---------------- segment mask ----------------
__global__ __launch_bounds__(64) void mask_kernel(const int* __restrict__ seg, float* __restrict__ mask) {
  __shared__ int mn[16], mx[16];
  const int b = blockIdx.x, tid = threadIdx.x;
  if (tid < 16) {
    const int* p = seg + (long)b * 4096 + tid * 256;
    int lo = p[0], hi = p[0];
    for (int i = 1; i < 256; i++) { int v = p[i]; lo = min(lo, v); hi = max(hi, v); }
    mn[tid] = lo; mx[tid] = hi;
  }
  __syncthreads();
  if (tid < 16) {
    const int g = tid;
    float row[16]; float s = 0.f;
    for (int h = 0; h < 16; h++) {
      float o = (mn[g] <= mx[h] && mx[g] >= mn[h]) ? 1.f : 0.f;
      row[h] = o; s += o;
    }
    const float inv = 1.f / s;
    for (int h = 0; h < 16; h++) mask[((long)b * 16 + g) * 16 + h] = row[h] * inv;
  }
}

// ---------------- mask-mix of P2 (folds 1/n) ----------------
__global__ __launch_bounds__(256) void mix_kernel(
    const float* __restrict__ P2, const float* __restrict__ mask, bf16* __restrict__ amix)
{
  const int z = blockIdx.x;          // b*16 + g
  const int b = z >> 4;
  float m[16];
#pragma unroll
  for (int h = 0; h < 16; h++) m[h] = mask[(long)z * 16 + h] * (1.f / 256.f);
  const float* Pb = P2 + (long)b * 16 * 16384;
  bf16* Ab = amix + (long)z * 16384;
#pragma unroll 4
  for (int j = 0; j < 16; j++) {
    int c = j * 256 + threadIdx.x;
    float ax = 0, ay = 0, az = 0, aw = 0;
#pragma unroll
    for (int h = 0; h < 16; h++) {
      float4 p = ((const float4*)(Pb + (long)h * 16384))[c];
      ax += m[h] * p.x; ay += m[h] * p.y; az += m[h] * p.z; aw += m[h] * p.w;
    }
    bf16x4 o; o[0] = (bf16)ax; o[1] = (bf16)ay; o[2] = (bf16)az; o[3] = (bf16)aw;
    *(bf16x4*)&Ab[(long)c * 4] = o;
  }
}

// ---------------- launch ----------------
extern "C" void kernel_launch(void* const* d_in, const int* in_sizes, int n_in,
                              void* d_out, int out_size, void* d_ws, size_t ws_size,
                              hipStream_t stream)
{
  const float* x0    = (const float*)d_in[0];
  const int*   seg   = (const int*)d_in[1];
  const float* lnw   = (const float*)d_in[2];
  const float* lnb   = (const float*)d_in[3];
  const float* W1    = (const float*)d_in[4];
  const float* b1    = (const float*)d_in[5];
  const float* gamma = (const float*)d_in[6];
  const float* beta  = (const float*)d_in[7];
  const float* W2    = (const float*)d_in[8];
  const float* b2    = (const float*)d_in[9];
  const float* wrel  = (const float*)d_in[10];
  float* out = (float*)d_out;
  char* ws = (char*)d_ws;

  bf16*   w1t   = (bf16*)(ws + OFF_W1T);
  bf16*   w2t   = (bf16*)(ws + OFF_W2T);
  float2* tab   = (float2*)(ws + OFF_TAB);
  bf16*   xn    = (bf16*)(ws + OFF_XN);
  bf16*   ker   = (bf16*)(ws + OFF_KER);
  bf16*   qq    = (bf16*)(ws + OFF_QQ);
  bf16*   qk    = (bf16*)(ws + OFF_QK);
  bf16*   kv4   = (bf16*)(ws + OFF_QQ);       // reuse (qq/qk dead after ker GEMM): 8x1536x512 bf16 = 12.6M
  bf16*   lq    = (bf16*)(ws + OFF_LQ);
  bf16*   u     = (bf16*)(ws + OFF_U);
  bf16*   zb    = (bf16*)(ws + OFF_Z);
  float*  P2    = (float*)(ws + OFF_Z);       // reuse (z dead after rope)
  bf16*   lk    = (bf16*)(ws + OFF_LK);
  bf16*   T1    = (bf16*)(ws + OFF_LK);       // reuse (lk dead after lkT)
  bf16*   lqT   = (bf16*)(ws + OFF_LQT);
  bf16*   amix  = (bf16*)(ws + OFF_LQT);      // reuse (lqT dead after P2)
  bf16*   kvT   = (bf16*)(ws + OFF_LQT + 4194304UL);
  bf16*   lkT   = (bf16*)(ws + OFF_LKT);
  float*  maskb = (float*)(ws + OFF_MASK);
  float*  invfd = (float*)(ws + OFF_INVF);
  bf16*   vTd   = (bf16*)d_out;               // vT lives in d_out, dead before final GEMM

  static float h_invf[64];
  for (int i = 0; i < 64; i++) h_invf[i] = powf(10000.0f, (float)i * (1.0f / 64.0f));
  hipMemcpyAsync(invfd, h_invf, 64 * sizeof(float), hipMemcpyHostToDevice, stream);

  // prep (independent)
  transpose_cast<float><<<dim3(50, 12, 1), 256, 0, stream>>>(W1, w1t, 768, 3200, 0, 0);
  transpose_cast<float><<<dim3(12, 24, 1), 256, 0, stream>>>(W2, w2t, 1536, 768, 0, 0);
  rope_table_kernel<<<1024, 256, 0, stream>>>(invfd, tab);
  mask_kernel<<<8, 64, 0, stream>>>(seg, maskb);

  // LN -> xn (bf16)
  ln_kernel<<<TT_, 256, 0, stream>>>(x0, lnw, lnb, xn);

  // GEMM1 full N=3200 (u, vT, z in one pass)
  gemm3s<EpiGemm1, false, true><<<dim3(256, 25, 1), 256, 0, stream>>>(
      xn, w1t, 768, 768, 768, 0, 0, 0, 0,
      nullptr, nullptr, 0, 0, 0, 0, 0, 0, 0, 1, EpiGemm1{b1, u, vTd, zb});

  // z -> 4 rope'd gate rows
  rope_kernel<<<TT_, 128, 0, stream>>>(zb, gamma, beta, tab, qq, qk, lq, lk);

  // lq/lk -> transposed (per b: 4096x128 -> 128x4096)
  transpose_cast<bf16><<<dim3(2, 64, 8), 256, 0, stream>>>(lq, lqT, 4096, 128, 524288, 524288);
  transpose_cast<bf16><<<dim3(2, 64, 8), 256, 0, stream>>>(lk, lkT, 4096, 128, 524288, 524288);

  // P2[b,h][s][k] = sum_{c in group h} lq[c][s] lk[c][k]  (K=256 per block)
  gemm3s<EpiF32, false, false><<<dim3(1, 1, 128), 256, 0, stream>>>(
      lqT, lkT, 4096, 4096, 256, 524288, 256, 524288, 256,
      nullptr, nullptr, 0, 0, 0, 0, 0, 0, 0, 16, EpiF32{P2, 262144, 16384, 128});

  // amix[b,g] = sum_h mask/n * P2[b,h]
  mix_kernel<<<128, 256, 0, stream>>>(P2, maskb, amix);

  // ker[b,g][n][m] = relu(qq.qk/n + bias)^2  (before kv4 overwrites qq/qk)
  gemm3s<EpiKer, false, false><<<dim3(2, 2, 128), 256, 0, stream>>>(
      qq, qk, 128, 128, 128, 32768, 0, 32768, 0,
      nullptr, nullptr, 0, 0, 0, 0, 0, 0, 0, 1, EpiKer{ker, wrel});

  // kv split-K x4: kv4[b][e][ks*128+s] = sum_{t in chunk ks} v[t][e] lk[t][s]
  gemm3s<EpiBf16, false, false><<<dim3(12, 1, 32), 256, 0, stream>>>(
      vTd, lkT, 4096, 4096, 1024, 6291456, 1024, 524288, 1024,
      nullptr, nullptr, 0, 0, 0, 0, 0, 0, 0, 4, EpiBf16{kv4, 786432, 128, 512});
  kvsum_kernel<<<6144, 256, 0, stream>>>(kv4, kvT);

  // T1[t][s] = sum_k lq[t][k] amix[b,g][s][k]
  gemm3s<EpiBf16, false, false><<<dim3(2, 1, 128), 256, 0, stream>>>(
      lq, amix, 128, 128, 128, 32768, 0, 16384, 0,
      nullptr, nullptr, 0, 0, 0, 0, 0, 0, 0, 1, EpiBf16{T1, 32768, 0, 128});

  // combine (dual-K): P = u * (ker@v + T1@kv), in-place over u
  gemm3s<EpiCombine, true, false><<<dim3(2, 12, 128), 256, 0, stream>>>(
      ker, vTd, 256, 4096, 256, 1048576, 65536, 6291456, 256,
      T1, kvT, 128, 128, 128, 524288, 32768, 196608, 0, 16, EpiCombine{u});

  // out = P@W2 + b2 + shortcut (vT in d_out is dead now)
  gemm3s<EpiFinal, false, true><<<dim3(256, 6, 1), 256, 0, stream>>>(
      u, w2t, 1536, 1536, 1536, 0, 0, 0, 0,
      nullptr, nullptr, 0, 0, 0, 0, 0, 0, 0, 1, EpiFinal{out, b2, x0});
}